// Round 13
// baseline (1142.137 us; speedup 1.0000x reference)
//
#include <hip/hip_runtime.h>
#include <cstdint>
#include <cstddef>

// Problem constants (fixed by the reference)
#define BSZ 4096
#define VN  1024
#define HN  1024
#define NSTEPS 10

static constexpr float INVB = 1.0f / 4096.0f;
static constexpr float L1R  = 1e-5f;
static constexpr float L2R  = 1e-4f;

typedef __attribute__((ext_vector_type(8)))  __bf16        bf16x8;
typedef __attribute__((ext_vector_type(8)))  unsigned short ushort8;
typedef __attribute__((ext_vector_type(16))) float          f32x16;

// ---------------------------------------------------------------------------
// bf16 helpers (RNE)
// ---------------------------------------------------------------------------
__device__ static inline unsigned short f2bf(float x){
  unsigned u = __float_as_uint(x);
  unsigned r = (u + 0x7FFFu + ((u >> 16) & 1u)) >> 16;
  return (unsigned short)r;
}
__device__ static inline float bf2f(unsigned short s){
  return __uint_as_float(((unsigned)s) << 16);
}

// async global->LDS, 16B per lane; LDS dest = wave-uniform base + lane*16
__device__ __forceinline__ void gload16(const void* g, void* l){
  __builtin_amdgcn_global_load_lds(
      (__attribute__((address_space(1))) void*)(g),
      (__attribute__((address_space(3))) void*)(l),
      16, 0, 0);
}

// ---------------------------------------------------------------------------
// Threefry-2x32 (bit-exact JAX PRNG)
// ---------------------------------------------------------------------------
#define TFR(x0,x1,r) { x0 += x1; x1 = ((x1)<<(r))|((x1)>>(32-(r))); x1 ^= x0; }

__host__ __device__ static inline void tf2x32(unsigned k0, unsigned k1,
                                              unsigned x0, unsigned x1,
                                              unsigned &o0, unsigned &o1)
{
  const unsigned ks2 = k0 ^ k1 ^ 0x1BD11BDAu;
  x0 += k0; x1 += k1;
  TFR(x0,x1,13) TFR(x0,x1,15) TFR(x0,x1,26) TFR(x0,x1,6)
  x0 += k1; x1 += ks2 + 1u;
  TFR(x0,x1,17) TFR(x0,x1,29) TFR(x0,x1,16) TFR(x0,x1,24)
  x0 += ks2; x1 += k0 + 2u;
  TFR(x0,x1,13) TFR(x0,x1,15) TFR(x0,x1,26) TFR(x0,x1,6)
  x0 += k0; x1 += k1 + 3u;
  TFR(x0,x1,17) TFR(x0,x1,29) TFR(x0,x1,16) TFR(x0,x1,24)
  x0 += k1; x1 += ks2 + 4u;
  TFR(x0,x1,13) TFR(x0,x1,15) TFR(x0,x1,26) TFR(x0,x1,6)
  x0 += ks2; x1 += k0 + 5u;
  o0 = x0; o1 = x1;
}

// jax.random.uniform element e — PARTITIONABLE threefry (JAX >= 0.4.30):
// counter (0, e); bits = xor-fold of the two outputs.
__device__ static inline float tf_uniform(unsigned k0, unsigned k1, unsigned e)
{
  unsigned o0, o1; tf2x32(k0, k1, 0u, e, o0, o1);
  const unsigned r = o0 ^ o1;
  return __uint_as_float((r >> 9) | 0x3f800000u) - 1.0f;
}

__device__ static inline float sigmoidf(float x){ return 1.0f/(1.0f+expf(-x)); }

// ---------------------------------------------------------------------------
// Small utility kernels
// ---------------------------------------------------------------------------
__global__ void zero_kernel(float* __restrict__ p, int n){
  int i = blockIdx.x*256 + threadIdx.x;
  if (i < n) p[i] = 0.0f;
}

// v0m = v0 with taus zeroed; v_cur=v0; bf16 copies for the MFMA path
__global__ void prep_kernel(const float* __restrict__ v0,
                            const int* __restrict__ tau,
                            float* __restrict__ v0m,
                            float* __restrict__ v_cur,
                            unsigned short* __restrict__ v0m_bf,
                            unsigned short* __restrict__ v_bf)
{
  int i = blockIdx.x*256 + threadIdx.x;     // exact grid BSZ*VN/256
  int b = i >> 10;
  int v = i & (VN-1);
  float x = v0[i];
  v_cur[i] = x;
  v_bf[i]  = f2bf(x);                        // 0/1 exact
  int t0 = tau[2*b], t1 = tau[2*b+1];
  float xm = (v==t0 || v==t1) ? 0.0f : x;
  v0m[i]    = xm;
  v0m_bf[i] = f2bf(xm);
}

// WT[v][h] = W[h][v] for both weight matrices (blockIdx.z selects)
__global__ void transpose_kernel(const float* __restrict__ Wa,
                                 const float* __restrict__ Wp,
                                 float* __restrict__ WTa,
                                 float* __restrict__ WTp)
{
  __shared__ float tile[32][33];
  const float* in = blockIdx.z ? Wp : Wa;
  float* out      = blockIdx.z ? WTp : WTa;
  int x  = blockIdx.x*32 + threadIdx.x;
  int y0 = blockIdx.y*32;
  for (int j = threadIdx.y; j < 32; j += 8)
    tile[j][threadIdx.x] = in[(size_t)(y0+j)*VN + x];
  __syncthreads();
  int xo  = y0 + threadIdx.x;
  int yo0 = blockIdx.x*32;
  for (int j = threadIdx.y; j < 32; j += 8)
    out[(size_t)(yo0+j)*HN + xo] = tile[threadIdx.x][j];
}

// transpose fp32 [BSZ][1024] -> bf16 (RNE) [1024][BSZ], FUSED column sum
__global__ void transpose_to_bf(const float* __restrict__ X,
                                unsigned short* __restrict__ XT,
                                float* __restrict__ cs)
{
  __shared__ float tile[32][33];
  const int tx = threadIdx.x, ty = threadIdx.y;
  int x  = blockIdx.x*32 + tx;            // col 0..1023
  int y0 = blockIdx.y*32;                 // row base 0..4095
  for (int j = ty; j < 32; j += 8)
    tile[j][tx] = X[(size_t)(y0+j)*1024 + x];
  __syncthreads();
  int xo  = y0 + tx;                      // b index in output row
  int yo0 = blockIdx.x*32;                // output row
  for (int j = ty; j < 32; j += 8)
    XT[(size_t)(yo0+j)*BSZ + xo] = f2bf(tile[tx][j]);
  float s = tile[ty][tx] + tile[ty+8][tx] + tile[ty+16][tx] + tile[ty+24][tx];
  __syncthreads();
  tile[ty][tx] = s;
  __syncthreads();
  if (ty == 0){
    float t = 0.f;
    #pragma unroll
    for (int j = 0; j < 8; j++) t += tile[j][tx];
    atomicAdd(cs + x, t);
  }
}

// hi/lo bf16 split of Wa, Wp (row-major) and Wa^T (from fp32 WTa)
__global__ void split_weights(const float* __restrict__ Wa,
                              const float* __restrict__ Wp,
                              const float* __restrict__ WTa,
                              unsigned short* __restrict__ WaHi,
                              unsigned short* __restrict__ WaLo,
                              unsigned short* __restrict__ WpHi,
                              unsigned short* __restrict__ WpLo,
                              unsigned short* __restrict__ WaTHi,
                              unsigned short* __restrict__ WaTLo)
{
  size_t i = (size_t)blockIdx.x*256 + threadIdx.x;   // grid HN*VN/256
  float w = Wa[i];  unsigned short h = f2bf(w);
  WaHi[i] = h;  WaLo[i] = f2bf(w - bf2f(h));
  w = Wp[i];  h = f2bf(w);
  WpHi[i] = h;  WpLo[i] = f2bf(w - bf2f(h));
  w = WTa[i]; h = f2bf(w);
  WaTHi[i] = h; WaTLo[i] = f2bf(w - bf2f(h));
}

// ---------------------------------------------------------------------------
// MFMA NT GEMM with hi/lo bf16 split B and fused epilogue.
//   C[m][n] = sum_k A[m][k]*(Bhi[n][k]+Blo[n][k]) + bias[n]
// Tile 128x128 (m97 geometry), BK=64; 4 waves as 2x2 grid of 64x64
// sub-tiles (each wave: 2 A-frags x 2 B-frag-pairs -> 6 LDS reads per
// chunk feed 8 MFMAs = 0.75 reads/MFMA, 2x better than the 64x64 tile's
// 1.5 — the 64x64 step was LDS-read-BW-bound at ~15us/step floor).
// LDS 48 KB, grid (8,32)=256 blocks = 1/CU. XCD-bijective swizzle.
// Per-output K-accumulation order unchanged (kt -> s -> hi -> bh,bl)
// -> bit-identical samples vs R10/R12.
// MODE 0: sample -> bf16 out        (Gibbs H-step / V-steps 0..8)
// MODE 1: sample -> bf16 + fp32 out (last V-step)
// MODE 2: sigmoid -> fp32           (sig_k)
// MODE 3: raw pre -> fp32           (pre0a / pre0p)
// ---------------------------------------------------------------------------
#define GM 128
#define GN 128
#define GK 64

template<int MODE>
__global__ __launch_bounds__(256) void mfma_nt(
    const unsigned short* __restrict__ A,     // [M][1024] bf16 (binary)
    const unsigned short* __restrict__ Bhi,   // [N][1024] bf16
    const unsigned short* __restrict__ Blo,   // [N][1024] bf16
    const float* __restrict__ bias,           // [N]
    unsigned short* __restrict__ out_bf,      // MODE 0,1
    float* __restrict__ out_f,                // MODE 1,2,3
    unsigned key0, unsigned key1)
{
  constexpr int K = 1024;
  constexpr int N = 1024;
  __shared__ ushort8 ldsA [GM*8];     // 16 KB
  __shared__ ushort8 ldsBh[GN*8];     // 16 KB
  __shared__ ushort8 ldsBl[GN*8];     // 16 KB

  // XCD-bijective swizzle: 256 wgs / 8 XCDs = 32 contiguous per XCD
  const int orig = blockIdx.x + gridDim.x * blockIdx.y;   // 0..255
  const int swz  = (orig & 7) * 32 + (orig >> 3);
  const int bx   = swz & 7, by = swz >> 3;
  const int m0   = by*GM, n0 = bx*GN;

  const int tid  = threadIdx.x;
  const int lane = tid & 63, w = tid >> 6;
  const int wm = w >> 1, wn = w & 1;       // 2x2 wave grid over 64x64 tiles
  const int l31 = lane & 31, hi = lane >> 5;
  const int rsub = lane >> 3;         // 0..7
  const int cch  = lane & 7;          // chunk 0..7

  f32x16 acc00 = {}, acc01 = {}, acc10 = {}, acc11 = {};

  const int arow0 = wm*64 + l31;      // wave's A rows: arow0, arow0+32
  const int brow0 = wn*64 + l31;      // wave's B rows: brow0, brow0+32
  const int aswz  = arow0 & 7;        // (arow0+32)&7 == arow0&7
  const int bswz  = brow0 & 7;
  const int aidx0 = arow0*8,      aidx1 = (arow0+32)*8;
  const int bidx0 = brow0*8,      bidx1 = (brow0+32)*8;

  for (int kt = 0; kt < K/GK; ++kt){
    __syncthreads();
    const size_t kbase = (size_t)kt*GK;
    #pragma unroll
    for (int p = 0; p < 4; p++){
      const int row  = p*32 + w*8 + rsub;     // 0..127, each exactly once
      const int csrc = cch ^ (row & 7);
      gload16(A   + (size_t)(m0+row)*K + kbase + csrc*8, &ldsA [(p*32 + w*8)*8]);
      gload16(Bhi + (size_t)(n0+row)*K + kbase + csrc*8, &ldsBh[(p*32 + w*8)*8]);
      gload16(Blo + (size_t)(n0+row)*K + kbase + csrc*8, &ldsBl[(p*32 + w*8)*8]);
    }
    __syncthreads();   // drains vmcnt before barrier (compiler-inserted)

    #pragma unroll
    for (int s = 0; s < 4; s++){
      const int c = s*2 + hi;
      const bf16x8 a0  = __builtin_bit_cast(bf16x8, ldsA [aidx0 + (c ^ aswz)]);
      const bf16x8 a1  = __builtin_bit_cast(bf16x8, ldsA [aidx1 + (c ^ aswz)]);
      const bf16x8 bh0 = __builtin_bit_cast(bf16x8, ldsBh[bidx0 + (c ^ bswz)]);
      const bf16x8 bl0 = __builtin_bit_cast(bf16x8, ldsBl[bidx0 + (c ^ bswz)]);
      const bf16x8 bh1 = __builtin_bit_cast(bf16x8, ldsBh[bidx1 + (c ^ bswz)]);
      const bf16x8 bl1 = __builtin_bit_cast(bf16x8, ldsBl[bidx1 + (c ^ bswz)]);
      acc00 = __builtin_amdgcn_mfma_f32_32x32x16_bf16(a0, bh0, acc00, 0, 0, 0);
      acc00 = __builtin_amdgcn_mfma_f32_32x32x16_bf16(a0, bl0, acc00, 0, 0, 0);
      acc01 = __builtin_amdgcn_mfma_f32_32x32x16_bf16(a0, bh1, acc01, 0, 0, 0);
      acc01 = __builtin_amdgcn_mfma_f32_32x32x16_bf16(a0, bl1, acc01, 0, 0, 0);
      acc10 = __builtin_amdgcn_mfma_f32_32x32x16_bf16(a1, bh0, acc10, 0, 0, 0);
      acc10 = __builtin_amdgcn_mfma_f32_32x32x16_bf16(a1, bl0, acc10, 0, 0, 0);
      acc11 = __builtin_amdgcn_mfma_f32_32x32x16_bf16(a1, bh1, acc11, 0, 0, 0);
      acc11 = __builtin_amdgcn_mfma_f32_32x32x16_bf16(a1, bl1, acc11, 0, 0, 0);
    }
  }

  // epilogue: C/D layout col=lane&31, row=(reg&3)+8*(reg>>2)+4*(lane>>5)
  #pragma unroll
  for (int ai = 0; ai < 2; ai++){
    #pragma unroll
    for (int bj = 0; bj < 2; bj++){
      const f32x16 acc = ai ? (bj ? acc11 : acc10) : (bj ? acc01 : acc00);
      const int n  = n0 + wn*64 + bj*32 + l31;
      const float bv = bias[n];
      const int mbase = m0 + wm*64 + ai*32 + 4*hi;
      #pragma unroll
      for (int r = 0; r < 16; r++){
        const int m = mbase + (r&3) + 8*(r>>2);
        const float pre = acc[r] + bv;
        const size_t o = (size_t)m*N + n;
        if constexpr (MODE == 0 || MODE == 1){
          const float p = sigmoidf(pre);
          const float u = tf_uniform(key0, key1, (unsigned)(m*N + n));
          out_bf[o] = (u < p) ? (unsigned short)0x3F80 : (unsigned short)0;
          if constexpr (MODE == 1) out_f[o] = (u < p) ? 1.0f : 0.0f;
        } else if constexpr (MODE == 2){
          out_f[o] = sigmoidf(pre);
        } else {
          out_f[o] = pre;
        }
      }
    }
  }
}

// ---------------------------------------------------------------------------
// MFMA gradient GEMM (NT over transposed operands, K = BSZ = 4096).
// NPROD==2 (amp):  gW += INVB*(A1*B1^T - A2*B2^T) + L2*W + L1*sign(W)
// NPROD==1 (ph):   gW += INVB*(A1*B1^T)           + L2*W + L1*sign(W)
// ---------------------------------------------------------------------------
template<int NPROD>
__global__ __launch_bounds__(256) void mfma_grad(
    const unsigned short* __restrict__ A1,   // [1024][4096] bf16
    const unsigned short* __restrict__ B1,   // [1024][4096] bf16
    const unsigned short* __restrict__ A2,
    const unsigned short* __restrict__ B2,
    const float* __restrict__ Wreg,
    float* __restrict__ gW)
{
  constexpr int K = BSZ;
  __shared__ ushort8 lA1[64*8];
  __shared__ ushort8 lB1[64*8];
  __shared__ ushort8 lA2[(NPROD==2)?64*8:1];
  __shared__ ushort8 lB2[(NPROD==2)?64*8:1];

  const int tid  = threadIdx.x;
  const int m0   = blockIdx.y*64, n0 = blockIdx.x*64;
  const int lane = tid & 63, w = tid >> 6;
  const int wm = w >> 1, wn = w & 1;
  const int l31 = lane & 31, hi = lane >> 5;
  const int srow = tid >> 3, sc = tid & 7;

  f32x16 acc1a = {}, acc1b = {}, acc2a = {}, acc2b = {};

  const int arow = wm*32 + l31;
  const int brow = wn*32 + l31;
  const int aswz = arow & 7, bswz = brow & 7;
  const int aidx = arow*8,  bidx = brow*8;

  for (int kt = 0; kt < K/64; ++kt){
    __syncthreads();
    const size_t kof = (size_t)kt*64 + sc*8;
    #pragma unroll
    for (int p = 0; p < 2; p++){
      const int row = p*32 + srow;
      const int c = sc ^ (row & 7);
      lA1[row*8 + c] = *(const ushort8*)(A1 + (size_t)(m0+row)*K + kof);
      lB1[row*8 + c] = *(const ushort8*)(B1 + (size_t)(n0+row)*K + kof);
      if constexpr (NPROD==2){
        lA2[row*8 + c] = *(const ushort8*)(A2 + (size_t)(m0+row)*K + kof);
        lB2[row*8 + c] = *(const ushort8*)(B2 + (size_t)(n0+row)*K + kof);
      }
    }
    __syncthreads();
    #pragma unroll
    for (int s = 0; s < 4; s++){
      const int c = s*2 + hi;
      const bf16x8 a1 = __builtin_bit_cast(bf16x8, lA1[aidx + (c ^ aswz)]);
      const bf16x8 b1 = __builtin_bit_cast(bf16x8, lB1[bidx + (c ^ bswz)]);
      if (s & 1) acc1b = __builtin_amdgcn_mfma_f32_32x32x16_bf16(a1, b1, acc1b, 0,0,0);
      else       acc1a = __builtin_amdgcn_mfma_f32_32x32x16_bf16(a1, b1, acc1a, 0,0,0);
      if constexpr (NPROD==2){
        const bf16x8 a2 = __builtin_bit_cast(bf16x8, lA2[aidx + (c ^ aswz)]);
        const bf16x8 b2 = __builtin_bit_cast(bf16x8, lB2[bidx + (c ^ bswz)]);
        if (s & 1) acc2b = __builtin_amdgcn_mfma_f32_32x32x16_bf16(a2, b2, acc2b, 0,0,0);
        else       acc2a = __builtin_amdgcn_mfma_f32_32x32x16_bf16(a2, b2, acc2a, 0,0,0);
      }
    }
  }

  const int n = n0 + wn*32 + l31;
  #pragma unroll
  for (int r = 0; r < 16; r++){
    const int m = m0 + wm*32 + 4*hi + (r&3) + 8*(r>>2);
    const size_t o = (size_t)m*VN + n;
    float val;
    if constexpr (NPROD==2)
      val = INVB*((acc1a[r]+acc1b[r]) - (acc2a[r]+acc2b[r]));
    else
      val = INVB*(acc1a[r]+acc1b[r]);
    const float wv = Wreg[o];
    const float sg = (wv>0.f)?1.f:((wv<0.f)?-1.f:0.f);
    gW[o] += val + L2R*wv + L1R*sg;
  }
}

// ---------------------------------------------------------------------------
// Fused coef + ramp kernel (Taylor-3 differentials + fp64 tail; see R7)
// ---------------------------------------------------------------------------
__global__ __launch_bounds__(256) void coef_ramp_kernel(
    const float* __restrict__ pre0a, const float* __restrict__ pre0p,
    const float* __restrict__ WTa,   const float* __restrict__ WTp,
    const float* __restrict__ v0,
    const float* __restrict__ vbA,   const float* __restrict__ vbP,
    const int*   __restrict__ tau,   const int*   __restrict__ basis,
    const float* __restrict__ unit,
    float* __restrict__ coefRe, float* __restrict__ coefIm,
    float* __restrict__ tmpA,   float* __restrict__ tmpP,
    float* __restrict__ Ramp,   float* __restrict__ Iph)
{
  const int b = blockIdx.x;
  const int t = threadIdx.x;
  const int t0 = tau[2*b], t1 = tau[2*b+1];

  float d[6] = {0,0,0,0,0,0};
  float st_sa[4], st_sp[4], st_a0[4], st_a1[4], st_p0[4], st_p1[4];

  #pragma unroll
  for (int i = 0; i < 4; i++){
    const int h = t + i*256;
    const float pa = pre0a[(size_t)b*HN + h], pp = pre0p[(size_t)b*HN + h];
    const float a0 = WTa[(size_t)t0*HN + h], a1 = WTa[(size_t)t1*HN + h];
    const float p0 = WTp[(size_t)t0*HN + h], p1 = WTp[(size_t)t1*HN + h];
    const float sa  = sigmoidf(pa);
    const float sp  = sigmoidf(pp);
    const float s1a = sa*(1.f-sa), ta2 = 1.f-2.f*sa, s2a = s1a*ta2;
    const float s1p = sp*(1.f-sp), tp2 = 1.f-2.f*sp, s2p = s1p*tp2;
    const float a01 = a0 + a1, p01 = p0 + p1;
    d[0] += a1 *(sa + a1 *(0.5f*s1a + 0.16666667f*a1 *s2a));
    d[1] += a0 *(sa + a0 *(0.5f*s1a + 0.16666667f*a0 *s2a));
    d[2] += a01*(sa + a01*(0.5f*s1a + 0.16666667f*a01*s2a));
    d[3] += p1 *(sp + p1 *(0.5f*s1p + 0.16666667f*p1 *s2p));
    d[4] += p0 *(sp + p0 *(0.5f*s1p + 0.16666667f*p0 *s2p));
    d[5] += p01*(sp + p01*(0.5f*s1p + 0.16666667f*p01*s2p));
    st_sa[i]=sa; st_sp[i]=sp; st_a0[i]=a0; st_a1[i]=a1; st_p0[i]=p0; st_p1[i]=p1;
  }

  __shared__ float red[6][4];
  __shared__ float lcr[4], lci[4];
  const int lane = t & 63, wv = t >> 6;
  #pragma unroll
  for (int i=0;i<6;i++){
    float x = d[i];
    for (int off=32; off>0; off>>=1) x += __shfl_down(x, off);
    if (lane==0) red[i][wv] = x;
  }
  __syncthreads();

  if (t==0){
    double ds[6];
    #pragma unroll
    for (int i=0;i<6;i++)
      ds[i] = (double)red[i][0]+red[i][1]+red[i][2]+red[i][3];

    const int bas0 = basis[(size_t)b*VN + t0], bas1 = basis[(size_t)b*VN + t1];
    const int x0 = (int)v0[(size_t)b*VN + t0], x1 = (int)v0[(size_t)b*VN + t1];
    const double A0 = vbA[t0], A1 = vbA[t1], P0 = vbP[t0], P1 = vbP[t1];

    double la[4], th[4];
    la[0]=0.0;                th[0]=0.0;
    la[1]=0.5*(A1+ds[0]);     th[1]=0.5*(P1+ds[3]);
    la[2]=0.5*(A0+ds[1]);     th[2]=0.5*(P0+ds[4]);
    la[3]=0.5*(A0+A1+ds[2]);  th[3]=0.5*(P0+P1+ds[5]);

    double wR[4], wI[4], sr=0.0, si=0.0;
    #pragma unroll
    for (int c=0;c<4;c++){
      const int s0 = (c>>1)&1, s1 = c&1;
      const float* u0 = unit + (((size_t)bas0*2 + x0)*2 + s0)*2;
      const float* u1 = unit + (((size_t)bas1*2 + x1)*2 + s1)*2;
      const double uR = (double)u0[0]*u1[0] - (double)u0[1]*u1[1];
      const double uI = (double)u0[0]*u1[1] + (double)u0[1]*u1[0];
      const double e  = exp(la[c]);
      const double cs = cos(th[c]), sn = sin(th[c]);
      wR[c] = e*(uR*cs - uI*sn);
      wI[c] = e*(uR*sn + uI*cs);
      sr += wR[c]; si += wI[c];
    }
    const double dd = sr*sr + si*si;
    #pragma unroll
    for (int c=0;c<4;c++){
      const float cr = (float)((wR[c]*sr + wI[c]*si)/dd);
      const float ci = (float)((wI[c]*sr - wR[c]*si)/dd);
      coefRe[b*4+c] = cr;  coefIm[b*4+c] = ci;
      lcr[c] = cr;         lci[c] = ci;
    }
    atomicAdd(tmpA + t0, lcr[2]+lcr[3]);
    atomicAdd(tmpA + t1, lcr[1]+lcr[3]);
    atomicAdd(tmpP + t0, lci[2]+lci[3]);
    atomicAdd(tmpP + t1, lci[1]+lci[3]);
  }
  __syncthreads();

  const float cr0=lcr[0], cr1=lcr[1], cr2=lcr[2], cr3=lcr[3];
  const float ci0=lci[0], ci1=lci[1], ci2=lci[2], ci3=lci[3];

  #pragma unroll
  for (int i = 0; i < 4; i++){
    const int h = t + i*256;
    const float sa = st_sa[i], sp = st_sp[i];
    const float a0 = st_a0[i], a1 = st_a1[i], p0 = st_p0[i], p1 = st_p1[i];
    const float s1a = sa*(1.f-sa), ta2 = 1.f-2.f*sa;
    const float s2a = s1a*ta2,     s3a = s1a*(ta2*ta2 - 2.f*s1a);
    const float s1p = sp*(1.f-sp), tp2 = 1.f-2.f*sp;
    const float s2p = s1p*tp2,     s3p = s1p*(tp2*tp2 - 2.f*s1p);
    const float a01 = a0 + a1, p01 = p0 + p1;
    const float sgA1 = sa + a1 *(s1a + a1 *(0.5f*s2a + 0.16666667f*a1 *s3a));
    const float sgA0 = sa + a0 *(s1a + a0 *(0.5f*s2a + 0.16666667f*a0 *s3a));
    const float sgA01= sa + a01*(s1a + a01*(0.5f*s2a + 0.16666667f*a01*s3a));
    const float sgP1 = sp + p1 *(s1p + p1 *(0.5f*s2p + 0.16666667f*p1 *s3p));
    const float sgP0 = sp + p0 *(s1p + p0 *(0.5f*s2p + 0.16666667f*p0 *s3p));
    const float sgP01= sp + p01*(s1p + p01*(0.5f*s2p + 0.16666667f*p01*s3p));
    Ramp[(size_t)b*HN + h] = cr0*sa + cr1*sgA1 + cr2*sgA0 + cr3*sgA01;
    Iph [(size_t)b*HN + h] = ci0*sp + ci1*sgP1 + ci2*sgP0 + ci3*sgP01;
  }
}

// ---------------------------------------------------------------------------
// CSR build + grouped tau-column scatter
// ---------------------------------------------------------------------------
__global__ void csr_count(const int* __restrict__ tau, int* __restrict__ cnt){
  int b = blockIdx.x*256 + threadIdx.x;
  atomicAdd(cnt + tau[2*b],   1);
  atomicAdd(cnt + tau[2*b+1], 1);
}

__global__ __launch_bounds__(1024) void csr_scan(const int* __restrict__ cnt,
                                                 int* __restrict__ off,
                                                 int* __restrict__ cur){
  __shared__ int s[1024];
  const int t = threadIdx.x;
  s[t] = cnt[t];
  __syncthreads();
  for (int d=1; d<1024; d<<=1){
    int v = 0;
    if (t >= d) v = s[t-d];
    __syncthreads();
    s[t] += v;
    __syncthreads();
  }
  const int excl = (t==0) ? 0 : s[t-1];
  off[t] = excl; cur[t] = excl;
}

__global__ void csr_fill(const int* __restrict__ tau, int* __restrict__ cur,
                         int* __restrict__ list){
  int b = blockIdx.x*256 + threadIdx.x;
  int p0 = atomicAdd(cur + tau[2*b],   1); list[p0] = b;
  int p1 = atomicAdd(cur + tau[2*b+1], 1); list[p1] = b;
}

// one h per thread, grid (VN, 4); e-loop unrolled x2 for MLP [R11 win]
__global__ __launch_bounds__(256) void scatter_v2(
    const float* __restrict__ pre0a, const float* __restrict__ pre0p,
    const float* __restrict__ WTa,   const float* __restrict__ WTp,
    const int*   __restrict__ tau,
    const float* __restrict__ coefRe, const float* __restrict__ coefIm,
    const int* __restrict__ cnt, const int* __restrict__ off,
    const int* __restrict__ list,
    float* __restrict__ gWa, float* __restrict__ gWp)
{
  const int v = blockIdx.x;
  const int n = cnt[v];
  if (n == 0) return;
  const int o = off[v];
  const int c_lo = (v < 512) ? 2 : 1;
  const bool lo_half = (v < 512);

  const int h = blockIdx.y*256 + threadIdx.x;
  const float av = WTa[(size_t)v*HN + h];
  const float pv = WTp[(size_t)v*HN + h];
  float accA = 0.f, accP = 0.f;
  int e = o;
  for (; e + 2 <= o + n; e += 2){
    const int b0 = list[e], b1 = list[e+1];
    const int ot0 = lo_half ? tau[2*b0+1] : tau[2*b0];
    const int ot1 = lo_half ? tau[2*b1+1] : tau[2*b1];
    const float aoA0 = WTa[(size_t)ot0*HN + h], aoA1 = WTa[(size_t)ot1*HN + h];
    const float aoP0 = WTp[(size_t)ot0*HN + h], aoP1 = WTp[(size_t)ot1*HN + h];
    const float pa0 = pre0a[(size_t)b0*HN + h], pa1 = pre0a[(size_t)b1*HN + h];
    const float pp0 = pre0p[(size_t)b0*HN + h], pp1 = pre0p[(size_t)b1*HN + h];
    const float crl0 = coefRe[b0*4 + c_lo], cr30 = coefRe[b0*4 + 3];
    const float cil0 = coefIm[b0*4 + c_lo], ci30 = coefIm[b0*4 + 3];
    const float crl1 = coefRe[b1*4 + c_lo], cr31 = coefRe[b1*4 + 3];
    const float cil1 = coefIm[b1*4 + c_lo], ci31 = coefIm[b1*4 + 3];
    accA += crl0*sigmoidf(pa0 + av) + cr30*sigmoidf(pa0 + av + aoA0);
    accP += cil0*sigmoidf(pp0 + pv) + ci30*sigmoidf(pp0 + pv + aoP0);
    accA += crl1*sigmoidf(pa1 + av) + cr31*sigmoidf(pa1 + av + aoA1);
    accP += cil1*sigmoidf(pp1 + pv) + ci31*sigmoidf(pp1 + pv + aoP1);
  }
  if (e < o + n){
    const int b0 = list[e];
    const int ot0 = lo_half ? tau[2*b0+1] : tau[2*b0];
    const float aoA0 = WTa[(size_t)ot0*HN + h];
    const float aoP0 = WTp[(size_t)ot0*HN + h];
    const float pa0 = pre0a[(size_t)b0*HN + h];
    const float pp0 = pre0p[(size_t)b0*HN + h];
    const float crl0 = coefRe[b0*4 + c_lo], cr30 = coefRe[b0*4 + 3];
    const float cil0 = coefIm[b0*4 + c_lo], ci30 = coefIm[b0*4 + 3];
    accA += crl0*sigmoidf(pa0 + av) + cr30*sigmoidf(pa0 + av + aoA0);
    accP += cil0*sigmoidf(pp0 + pv) + ci30*sigmoidf(pp0 + pv + aoP0);
  }
  gWa[(size_t)h*VN + v] += -INVB*accA;
  gWp[(size_t)h*VN + v] +=  INVB*accP;
}

__global__ void final_small(
    const float* __restrict__ csV0m, const float* __restrict__ csVk,
    const float* __restrict__ csSigk, const float* __restrict__ csRamp,
    const float* __restrict__ csIph,
    const float* __restrict__ tmpA, const float* __restrict__ tmpP,
    float* __restrict__ gVa, float* __restrict__ gHa,
    float* __restrict__ gVp, float* __restrict__ gHp)
{
  const int j = blockIdx.x*256 + threadIdx.x;
  if (j < VN){
    gVa[j] = INVB*(csVk[j] - csV0m[j] - tmpA[j]);
    gVp[j] = INVB*tmpP[j];
  }
  if (j < HN){
    gHa[j] = INVB*(csSigk[j] - csRamp[j]);
    gHp[j] = INVB*csIph[j];
  }
}

// ---------------------------------------------------------------------------
extern "C" void kernel_launch(void* const* d_in, const int* in_sizes, int n_in,
                              void* d_out, int out_size, void* d_ws, size_t ws_size,
                              hipStream_t stream)
{
  const float* v0    = (const float*)d_in[0];
  const int*   basis = (const int*)  d_in[1];
  const int*   tau   = (const int*)  d_in[2];
  const float* unit  = (const float*)d_in[3];
  const float* Wa    = (const float*)d_in[4];
  const float* vbA   = (const float*)d_in[5];
  const float* hbA   = (const float*)d_in[6];
  const float* Wp    = (const float*)d_in[7];
  const float* vbP   = (const float*)d_in[8];
  const float* hbP   = (const float*)d_in[9];

  // workspace layout (~156 MB)
  float* ws    = (float*)d_ws;
  float* v0m   = ws;  ws += (size_t)BSZ*VN;
  float* v_cur = ws;  ws += (size_t)BSZ*VN;
  float* h_buf = ws;  ws += (size_t)BSZ*HN;   // used as sig_k
  float* WTa   = ws;  ws += (size_t)VN*HN;    // } dead after scatter_v2
  float* WTp   = ws;  ws += (size_t)VN*HN;    // }   -> sigkT (8MB)
  float* pre0a = ws;  ws += (size_t)BSZ*HN;   // dead after scatter -> v0mT+vkT
  float* pre0p = ws;  ws += (size_t)BSZ*HN;   // dead after scatter -> RampT+IphT
  float* Ramp  = ws;  ws += (size_t)BSZ*HN;
  float* Iph   = ws;  ws += (size_t)BSZ*HN;
  float* coefRe= ws;  ws += (size_t)BSZ*4;
  float* coefIm= ws;  ws += (size_t)BSZ*4;
  float* tmpA  = ws;  ws += VN;
  float* tmpP  = ws;  ws += VN;
  float* csV0m = ws;  ws += VN;
  float* csVk  = ws;  ws += VN;
  float* csSigk= ws;  ws += HN;
  float* csRamp= ws;  ws += HN;
  float* csIph = ws;  ws += HN;
  int*   csrCnt = (int*)ws;  ws += VN;
  int*   csrOff = (int*)ws;  ws += VN;
  int*   csrCur = (int*)ws;  ws += VN;
  int*   csrLst = (int*)ws;  ws += 2*BSZ;
  // bf16 buffers
  unsigned short* v_bf    = (unsigned short*)ws;  ws += (size_t)BSZ*VN/2;
  unsigned short* h_bf    = (unsigned short*)ws;  ws += (size_t)BSZ*HN/2;
  unsigned short* v0m_bf  = (unsigned short*)ws;  ws += (size_t)BSZ*VN/2;
  unsigned short* WaHi    = (unsigned short*)ws;  ws += (size_t)HN*VN/2;
  unsigned short* WaLo    = (unsigned short*)ws;  ws += (size_t)HN*VN/2;
  unsigned short* WpHi    = (unsigned short*)ws;  ws += (size_t)HN*VN/2;
  unsigned short* WpLo    = (unsigned short*)ws;  ws += (size_t)HN*VN/2;
  unsigned short* WaTHi   = (unsigned short*)ws;  ws += (size_t)HN*VN/2;
  unsigned short* WaTLo   = (unsigned short*)ws;  ws += (size_t)HN*VN/2;

  float* sig_k = h_buf;
  // transposed bf16 gradient operands, aliased into dead regions:
  unsigned short* v0mT  = (unsigned short*)pre0a;                  // 8 MB
  unsigned short* vkT   = v0mT + (size_t)VN*BSZ;                   // 8 MB
  unsigned short* RampT = (unsigned short*)pre0p;                  // 8 MB
  unsigned short* IphT  = RampT + (size_t)HN*BSZ;                  // 8 MB
  unsigned short* sigkT = (unsigned short*)WTa;                    // 8 MB

  float* out = (float*)d_out;
  float* gWa = out;
  float* gVa = gWa + (size_t)HN*VN;
  float* gHa = gVa + VN;
  float* gWp = gHa + HN;
  float* gVp = gWp + (size_t)HN*VN;
  float* gHp = gVp + VN;

  const dim3 gemm_grid(VN/GN, BSZ/GM);   // (8, 32) = 256 wgs, 1/CU
  const dim3 tr_grid(1024/32, BSZ/32);   // (32, 128)
  const dim3 tr_blk(32, 8);

  // 1) init
  zero_kernel<<<dim3(40), 256, 0, stream>>>(tmpA, 10*1024);
  zero_kernel<<<dim3((out_size+255)/256), 256, 0, stream>>>(out, out_size);
  prep_kernel<<<dim3(BSZ*VN/256), 256, 0, stream>>>(v0, tau, v0m, v_cur, v0m_bf, v_bf);
  transpose_kernel<<<dim3(VN/32, HN/32, 2), dim3(32,8), 0, stream>>>(Wa, Wp, WTa, WTp);
  split_weights<<<dim3(HN*VN/256), 256, 0, stream>>>(
      Wa, Wp, WTa, WaHi, WaLo, WpHi, WpLo, WaTHi, WaTLo);

  // 2) positive phase: pre0 via MFMA (raw-pre mode), then fused coef+ramp
  mfma_nt<3><<<gemm_grid, 256, 0, stream>>>(
      v0m_bf, WaHi, WaLo, hbA, nullptr, pre0a, 0u, 0u);
  mfma_nt<3><<<gemm_grid, 256, 0, stream>>>(
      v0m_bf, WpHi, WpLo, hbP, nullptr, pre0p, 0u, 0u);
  coef_ramp_kernel<<<dim3(BSZ), 256, 0, stream>>>(
      pre0a, pre0p, WTa, WTp, v0, vbA, vbP, tau, basis, unit,
      coefRe, coefIm, tmpA, tmpP, Ramp, Iph);

  // 2b) tau-column scatter (grouped, non-atomic) into zeroed gWa/gWp
  csr_count<<<dim3(BSZ/256), 256, 0, stream>>>(tau, csrCnt);
  csr_scan <<<dim3(1), 1024, 0, stream>>>(csrCnt, csrOff, csrCur);
  csr_fill <<<dim3(BSZ/256), 256, 0, stream>>>(tau, csrCur, csrLst);
  scatter_v2<<<dim3(VN, 4), 256, 0, stream>>>(
      pre0a, pre0p, WTa, WTp, tau, coefRe, coefIm,
      csrCnt, csrOff, csrLst, gWa, gWp);

  // 3) CD-k Gibbs chain on matrix cores (bit-exact JAX partitionable
  //    threefry); fp32 v_cur written only at the LAST V-step
  for (int i = 0; i < NSTEPS; i++){
    unsigned kh0, kh1, kv0, kv1;
    tf2x32(0u, 1234u, 0u, (unsigned)(2*i),   kh0, kh1);
    tf2x32(0u, 1234u, 0u, (unsigned)(2*i+1), kv0, kv1);
    mfma_nt<0><<<gemm_grid, 256, 0, stream>>>(
        v_bf, WaHi, WaLo, hbA, h_bf, nullptr, kh0, kh1);
    if (i < NSTEPS-1)
      mfma_nt<0><<<gemm_grid, 256, 0, stream>>>(
          h_bf, WaTHi, WaTLo, vbA, v_bf, nullptr, kv0, kv1);
    else
      mfma_nt<1><<<gemm_grid, 256, 0, stream>>>(
          h_bf, WaTHi, WaTLo, vbA, v_bf, v_cur, kv0, kv1);
  }
  mfma_nt<2><<<gemm_grid, 256, 0, stream>>>(
      v_bf, WaHi, WaLo, hbA, nullptr, sig_k, 0u, 0u);

  // 4) transpose-convert gradient operands (with FUSED column sums),
  //    then MFMA gradient GEMMs
  transpose_to_bf<<<tr_grid, tr_blk, 0, stream>>>(v0m,   v0mT,  csV0m);
  transpose_to_bf<<<tr_grid, tr_blk, 0, stream>>>(v_cur, vkT,   csVk);
  transpose_to_bf<<<tr_grid, tr_blk, 0, stream>>>(Ramp,  RampT, csRamp);
  transpose_to_bf<<<tr_grid, tr_blk, 0, stream>>>(Iph,   IphT,  csIph);
  transpose_to_bf<<<tr_grid, tr_blk, 0, stream>>>(sig_k, sigkT, csSigk);

  mfma_grad<2><<<dim3(VN/64, HN/64), 256, 0, stream>>>(
      sigkT, vkT, RampT, v0mT, Wa, gWa);
  mfma_grad<1><<<dim3(VN/64, HN/64), 256, 0, stream>>>(
      IphT, v0mT, nullptr, nullptr, Wp, gWp);

  final_small<<<dim3(4), 256, 0, stream>>>(
      csV0m, csVk, csSigk, csRamp, csIph, tmpA, tmpP, gVa, gHa, gVp, gHp);
}

// Round 14
// 935.823 us; speedup vs baseline: 1.2205x; 1.2205x over previous
//
#include <hip/hip_runtime.h>
#include <cstdint>
#include <cstddef>

// Problem constants (fixed by the reference)
#define BSZ 4096
#define VN  1024
#define HN  1024
#define NSTEPS 10

static constexpr float INVB = 1.0f / 4096.0f;
static constexpr float L1R  = 1e-5f;
static constexpr float L2R  = 1e-4f;

typedef __attribute__((ext_vector_type(8)))  __bf16        bf16x8;
typedef __attribute__((ext_vector_type(8)))  unsigned short ushort8;
typedef __attribute__((ext_vector_type(4)))  unsigned short ushort4v;
typedef __attribute__((ext_vector_type(4)))  float          f32x4;
typedef __attribute__((ext_vector_type(16))) float          f32x16;

// ---------------------------------------------------------------------------
// bf16 helpers (RNE)
// ---------------------------------------------------------------------------
__device__ static inline unsigned short f2bf(float x){
  unsigned u = __float_as_uint(x);
  unsigned r = (u + 0x7FFFu + ((u >> 16) & 1u)) >> 16;
  return (unsigned short)r;
}
__device__ static inline float bf2f(unsigned short s){
  return __uint_as_float(((unsigned)s) << 16);
}

// async global->LDS, 16B per lane; LDS dest = wave-uniform base + lane*16
__device__ __forceinline__ void gload16(const void* g, void* l){
  __builtin_amdgcn_global_load_lds(
      (__attribute__((address_space(1))) void*)(g),
      (__attribute__((address_space(3))) void*)(l),
      16, 0, 0);
}

// ---------------------------------------------------------------------------
// Threefry-2x32 (bit-exact JAX PRNG)
// ---------------------------------------------------------------------------
#define TFR(x0,x1,r) { x0 += x1; x1 = ((x1)<<(r))|((x1)>>(32-(r))); x1 ^= x0; }

__host__ __device__ static inline void tf2x32(unsigned k0, unsigned k1,
                                              unsigned x0, unsigned x1,
                                              unsigned &o0, unsigned &o1)
{
  const unsigned ks2 = k0 ^ k1 ^ 0x1BD11BDAu;
  x0 += k0; x1 += k1;
  TFR(x0,x1,13) TFR(x0,x1,15) TFR(x0,x1,26) TFR(x0,x1,6)
  x0 += k1; x1 += ks2 + 1u;
  TFR(x0,x1,17) TFR(x0,x1,29) TFR(x0,x1,16) TFR(x0,x1,24)
  x0 += ks2; x1 += k0 + 2u;
  TFR(x0,x1,13) TFR(x0,x1,15) TFR(x0,x1,26) TFR(x0,x1,6)
  x0 += k0; x1 += k1 + 3u;
  TFR(x0,x1,17) TFR(x0,x1,29) TFR(x0,x1,16) TFR(x0,x1,24)
  x0 += k1; x1 += ks2 + 4u;
  TFR(x0,x1,13) TFR(x0,x1,15) TFR(x0,x1,26) TFR(x0,x1,6)
  x0 += ks2; x1 += k0 + 5u;
  o0 = x0; o1 = x1;
}

// jax.random.uniform element e — PARTITIONABLE threefry (JAX >= 0.4.30):
// counter (0, e); bits = xor-fold of the two outputs.
__device__ static inline float tf_uniform(unsigned k0, unsigned k1, unsigned e)
{
  unsigned o0, o1; tf2x32(k0, k1, 0u, e, o0, o1);
  const unsigned r = o0 ^ o1;
  return __uint_as_float((r >> 9) | 0x3f800000u) - 1.0f;
}

__device__ static inline float sigmoidf(float x){ return 1.0f/(1.0f+expf(-x)); }

// ---------------------------------------------------------------------------
// Small utility kernels
// ---------------------------------------------------------------------------
__global__ void zero_kernel(float* __restrict__ p, int n){
  int i = blockIdx.x*256 + threadIdx.x;
  if (i < n) p[i] = 0.0f;
}

// v0m = v0 with taus zeroed; v_cur=v0; bf16 copies for the MFMA path
__global__ void prep_kernel(const float* __restrict__ v0,
                            const int* __restrict__ tau,
                            float* __restrict__ v0m,
                            float* __restrict__ v_cur,
                            unsigned short* __restrict__ v0m_bf,
                            unsigned short* __restrict__ v_bf)
{
  int i = blockIdx.x*256 + threadIdx.x;     // exact grid BSZ*VN/256
  int b = i >> 10;
  int v = i & (VN-1);
  float x = v0[i];
  v_cur[i] = x;
  v_bf[i]  = f2bf(x);                        // 0/1 exact
  int t0 = tau[2*b], t1 = tau[2*b+1];
  float xm = (v==t0 || v==t1) ? 0.0f : x;
  v0m[i]    = xm;
  v0m_bf[i] = f2bf(xm);
}

// WT[v][h] = W[h][v] for both weight matrices (blockIdx.z selects)
__global__ void transpose_kernel(const float* __restrict__ Wa,
                                 const float* __restrict__ Wp,
                                 float* __restrict__ WTa,
                                 float* __restrict__ WTp)
{
  __shared__ float tile[32][33];
  const float* in = blockIdx.z ? Wp : Wa;
  float* out      = blockIdx.z ? WTp : WTa;
  int x  = blockIdx.x*32 + threadIdx.x;
  int y0 = blockIdx.y*32;
  for (int j = threadIdx.y; j < 32; j += 8)
    tile[j][threadIdx.x] = in[(size_t)(y0+j)*VN + x];
  __syncthreads();
  int xo  = y0 + threadIdx.x;
  int yo0 = blockIdx.x*32;
  for (int j = threadIdx.y; j < 32; j += 8)
    out[(size_t)(yo0+j)*HN + xo] = tile[threadIdx.x][j];
}

// transpose fp32 [BSZ][1024] -> bf16 (RNE) [1024][BSZ], FUSED column sum
__global__ void transpose_to_bf(const float* __restrict__ X,
                                unsigned short* __restrict__ XT,
                                float* __restrict__ cs)
{
  __shared__ float tile[32][33];
  const int tx = threadIdx.x, ty = threadIdx.y;
  int x  = blockIdx.x*32 + tx;            // col 0..1023
  int y0 = blockIdx.y*32;                 // row base 0..4095
  for (int j = ty; j < 32; j += 8)
    tile[j][tx] = X[(size_t)(y0+j)*1024 + x];
  __syncthreads();
  int xo  = y0 + tx;                      // b index in output row
  int yo0 = blockIdx.x*32;                // output row
  for (int j = ty; j < 32; j += 8)
    XT[(size_t)(yo0+j)*BSZ + xo] = f2bf(tile[tx][j]);
  float s = tile[ty][tx] + tile[ty+8][tx] + tile[ty+16][tx] + tile[ty+24][tx];
  __syncthreads();
  tile[ty][tx] = s;
  __syncthreads();
  if (ty == 0){
    float t = 0.f;
    #pragma unroll
    for (int j = 0; j < 8; j++) t += tile[j][tx];
    atomicAdd(cs + x, t);
  }
}

// hi/lo bf16 split of Wa, Wp, Wa^T; hi-only of Wp^T (for bf16 scatter)
__global__ void split_weights(const float* __restrict__ Wa,
                              const float* __restrict__ Wp,
                              const float* __restrict__ WTa,
                              const float* __restrict__ WTp,
                              unsigned short* __restrict__ WaHi,
                              unsigned short* __restrict__ WaLo,
                              unsigned short* __restrict__ WpHi,
                              unsigned short* __restrict__ WpLo,
                              unsigned short* __restrict__ WaTHi,
                              unsigned short* __restrict__ WaTLo,
                              unsigned short* __restrict__ WpTHi)
{
  size_t i = (size_t)blockIdx.x*256 + threadIdx.x;   // grid HN*VN/256
  float w = Wa[i];  unsigned short h = f2bf(w);
  WaHi[i] = h;  WaLo[i] = f2bf(w - bf2f(h));
  w = Wp[i];  h = f2bf(w);
  WpHi[i] = h;  WpLo[i] = f2bf(w - bf2f(h));
  w = WTa[i]; h = f2bf(w);
  WaTHi[i] = h; WaTLo[i] = f2bf(w - bf2f(h));
  WpTHi[i] = f2bf(WTp[i]);
}

// ---------------------------------------------------------------------------
// MFMA NT GEMM with hi/lo bf16 split B and fused epilogue.
// Tile 64x64, BK=64; 4 waves as 2x2 grid of 32x32 sub-tiles (R12 form —
// verified fastest vs 128x64/2blk (R5) and 128x128/1blk (R13); the chain is
// TLP-limited at this shape, 4 blocks/CU wins).
// LDS 24 KB -> 4 blocks/CU. XCD-bijective block swizzle.
// K-accumulation order fixed -> bit-identical samples across rounds.
// MODE 0: sample -> bf16 out        (Gibbs H-step / V-steps 0..8)
// MODE 1: sample -> bf16 + fp32 out (last V-step)
// MODE 2: sigmoid -> fp32           (sig_k)
// MODE 3: raw pre -> fp32 + bf16    (pre0a / pre0p; bf16 copy for scatter)
// ---------------------------------------------------------------------------
#define GM 64
#define GN 64
#define GK 64

template<int MODE>
__global__ __launch_bounds__(256) void mfma_nt(
    const unsigned short* __restrict__ A,     // [M][1024] bf16 (binary)
    const unsigned short* __restrict__ Bhi,   // [N][1024] bf16
    const unsigned short* __restrict__ Blo,   // [N][1024] bf16
    const float* __restrict__ bias,           // [N]
    unsigned short* __restrict__ out_bf,      // MODE 0,1,3
    float* __restrict__ out_f,                // MODE 1,2,3
    unsigned key0, unsigned key1)
{
  constexpr int K = 1024;
  constexpr int N = 1024;
  __shared__ ushort8 ldsA [GM*8];     // 8 KB
  __shared__ ushort8 ldsBh[GN*8];     // 8 KB
  __shared__ ushort8 ldsBl[GN*8];     // 8 KB

  // XCD-bijective swizzle: 1024 wgs / 8 XCDs = 128 contiguous per XCD
  const int orig = blockIdx.x + gridDim.x * blockIdx.y;
  const int swz  = (orig & 7) * 128 + (orig >> 3);
  const int bx   = swz & 15, by = swz >> 4;
  const int m0   = by*GM, n0 = bx*GN;

  const int tid  = threadIdx.x;
  const int lane = tid & 63, w = tid >> 6;
  const int wm = w >> 1, wn = w & 1;       // 2x2 wave grid over 32x32 tiles
  const int l31 = lane & 31, hi = lane >> 5;
  const int rsub = lane >> 3;         // 0..7
  const int cch  = lane & 7;          // chunk 0..7

  f32x16 acc = {};

  const int arow = wm*32 + l31;       // wave's 32-row A band   (0..63)
  const int brow = wn*32 + l31;       // wave's 32-row B band   (0..63)
  const int aswz = arow & 7;
  const int bswz = brow & 7;
  const int aidx = arow*8;
  const int bidx = brow*8;

  for (int kt = 0; kt < K/GK; ++kt){
    __syncthreads();
    const size_t kbase = (size_t)kt*GK;
    #pragma unroll
    for (int p = 0; p < 2; p++){
      const int row  = p*32 + w*8 + rsub;
      const int csrc = cch ^ (row & 7);
      gload16(A   + (size_t)(m0+row)*K + kbase + csrc*8, &ldsA [(p*32 + w*8)*8]);
      gload16(Bhi + (size_t)(n0+row)*K + kbase + csrc*8, &ldsBh[(p*32 + w*8)*8]);
      gload16(Blo + (size_t)(n0+row)*K + kbase + csrc*8, &ldsBl[(p*32 + w*8)*8]);
    }
    __syncthreads();   // drains vmcnt before barrier (compiler-inserted)

    #pragma unroll
    for (int s = 0; s < 4; s++){
      const int c = s*2 + hi;
      const bf16x8 a  = __builtin_bit_cast(bf16x8, ldsA [aidx + (c ^ aswz)]);
      const bf16x8 bh = __builtin_bit_cast(bf16x8, ldsBh[bidx + (c ^ bswz)]);
      const bf16x8 bl = __builtin_bit_cast(bf16x8, ldsBl[bidx + (c ^ bswz)]);
      acc = __builtin_amdgcn_mfma_f32_32x32x16_bf16(a, bh, acc, 0, 0, 0);
      acc = __builtin_amdgcn_mfma_f32_32x32x16_bf16(a, bl, acc, 0, 0, 0);
    }
  }

  // epilogue: C/D layout col=lane&31, row=(reg&3)+8*(reg>>2)+4*(lane>>5)
  const int n  = n0 + wn*32 + l31;
  const float bv = bias[n];
  const int mbase = m0 + wm*32 + 4*hi;
  #pragma unroll
  for (int r = 0; r < 16; r++){
    const int m = mbase + (r&3) + 8*(r>>2);
    const float pre = acc[r] + bv;
    const size_t o = (size_t)m*N + n;
    if constexpr (MODE == 0 || MODE == 1){
      const float p = sigmoidf(pre);
      const float u = tf_uniform(key0, key1, (unsigned)(m*N + n));
      out_bf[o] = (u < p) ? (unsigned short)0x3F80 : (unsigned short)0;
      if constexpr (MODE == 1) out_f[o] = (u < p) ? 1.0f : 0.0f;
    } else if constexpr (MODE == 2){
      out_f[o] = sigmoidf(pre);
    } else {
      out_f[o]  = pre;
      out_bf[o] = f2bf(pre);
    }
  }
}

// ---------------------------------------------------------------------------
// MFMA gradient GEMM (NT over transposed operands, K = BSZ = 4096).
// NPROD==2 (amp):  gW += INVB*(A1*B1^T - A2*B2^T) + L2*W + L1*sign(W)
// NPROD==1 (ph):   gW += INVB*(A1*B1^T)           + L2*W + L1*sign(W)
// ---------------------------------------------------------------------------
template<int NPROD>
__global__ __launch_bounds__(256) void mfma_grad(
    const unsigned short* __restrict__ A1,   // [1024][4096] bf16
    const unsigned short* __restrict__ B1,   // [1024][4096] bf16
    const unsigned short* __restrict__ A2,
    const unsigned short* __restrict__ B2,
    const float* __restrict__ Wreg,
    float* __restrict__ gW)
{
  constexpr int K = BSZ;
  __shared__ ushort8 lA1[64*8];
  __shared__ ushort8 lB1[64*8];
  __shared__ ushort8 lA2[(NPROD==2)?64*8:1];
  __shared__ ushort8 lB2[(NPROD==2)?64*8:1];

  const int tid  = threadIdx.x;
  const int m0   = blockIdx.y*64, n0 = blockIdx.x*64;
  const int lane = tid & 63, w = tid >> 6;
  const int wm = w >> 1, wn = w & 1;
  const int l31 = lane & 31, hi = lane >> 5;
  const int srow = tid >> 3, sc = tid & 7;

  f32x16 acc1a = {}, acc1b = {}, acc2a = {}, acc2b = {};

  const int arow = wm*32 + l31;
  const int brow = wn*32 + l31;
  const int aswz = arow & 7, bswz = brow & 7;
  const int aidx = arow*8,  bidx = brow*8;

  for (int kt = 0; kt < K/64; ++kt){
    __syncthreads();
    const size_t kof = (size_t)kt*64 + sc*8;
    #pragma unroll
    for (int p = 0; p < 2; p++){
      const int row = p*32 + srow;
      const int c = sc ^ (row & 7);
      lA1[row*8 + c] = *(const ushort8*)(A1 + (size_t)(m0+row)*K + kof);
      lB1[row*8 + c] = *(const ushort8*)(B1 + (size_t)(n0+row)*K + kof);
      if constexpr (NPROD==2){
        lA2[row*8 + c] = *(const ushort8*)(A2 + (size_t)(m0+row)*K + kof);
        lB2[row*8 + c] = *(const ushort8*)(B2 + (size_t)(n0+row)*K + kof);
      }
    }
    __syncthreads();
    #pragma unroll
    for (int s = 0; s < 4; s++){
      const int c = s*2 + hi;
      const bf16x8 a1 = __builtin_bit_cast(bf16x8, lA1[aidx + (c ^ aswz)]);
      const bf16x8 b1 = __builtin_bit_cast(bf16x8, lB1[bidx + (c ^ bswz)]);
      if (s & 1) acc1b = __builtin_amdgcn_mfma_f32_32x32x16_bf16(a1, b1, acc1b, 0,0,0);
      else       acc1a = __builtin_amdgcn_mfma_f32_32x32x16_bf16(a1, b1, acc1a, 0,0,0);
      if constexpr (NPROD==2){
        const bf16x8 a2 = __builtin_bit_cast(bf16x8, lA2[aidx + (c ^ aswz)]);
        const bf16x8 b2 = __builtin_bit_cast(bf16x8, lB2[bidx + (c ^ bswz)]);
        if (s & 1) acc2b = __builtin_amdgcn_mfma_f32_32x32x16_bf16(a2, b2, acc2b, 0,0,0);
        else       acc2a = __builtin_amdgcn_mfma_f32_32x32x16_bf16(a2, b2, acc2a, 0,0,0);
      }
    }
  }

  const int n = n0 + wn*32 + l31;
  #pragma unroll
  for (int r = 0; r < 16; r++){
    const int m = m0 + wm*32 + 4*hi + (r&3) + 8*(r>>2);
    const size_t o = (size_t)m*VN + n;
    float val;
    if constexpr (NPROD==2)
      val = INVB*((acc1a[r]+acc1b[r]) - (acc2a[r]+acc2b[r]));
    else
      val = INVB*(acc1a[r]+acc1b[r]);
    const float wv = Wreg[o];
    const float sg = (wv>0.f)?1.f:((wv<0.f)?-1.f:0.f);
    gW[o] += val + L2R*wv + L1R*sg;
  }
}

// ---------------------------------------------------------------------------
// Fused coef + ramp kernel (Taylor-3 differentials + fp64 tail; see R7)
// ---------------------------------------------------------------------------
__global__ __launch_bounds__(256) void coef_ramp_kernel(
    const float* __restrict__ pre0a, const float* __restrict__ pre0p,
    const float* __restrict__ WTa,   const float* __restrict__ WTp,
    const float* __restrict__ v0,
    const float* __restrict__ vbA,   const float* __restrict__ vbP,
    const int*   __restrict__ tau,   const int*   __restrict__ basis,
    const float* __restrict__ unit,
    float* __restrict__ coefRe, float* __restrict__ coefIm,
    float* __restrict__ tmpA,   float* __restrict__ tmpP,
    float* __restrict__ Ramp,   float* __restrict__ Iph)
{
  const int b = blockIdx.x;
  const int t = threadIdx.x;
  const int t0 = tau[2*b], t1 = tau[2*b+1];

  float d[6] = {0,0,0,0,0,0};
  float st_sa[4], st_sp[4], st_a0[4], st_a1[4], st_p0[4], st_p1[4];

  #pragma unroll
  for (int i = 0; i < 4; i++){
    const int h = t + i*256;
    const float pa = pre0a[(size_t)b*HN + h], pp = pre0p[(size_t)b*HN + h];
    const float a0 = WTa[(size_t)t0*HN + h], a1 = WTa[(size_t)t1*HN + h];
    const float p0 = WTp[(size_t)t0*HN + h], p1 = WTp[(size_t)t1*HN + h];
    const float sa  = sigmoidf(pa);
    const float sp  = sigmoidf(pp);
    const float s1a = sa*(1.f-sa), ta2 = 1.f-2.f*sa, s2a = s1a*ta2;
    const float s1p = sp*(1.f-sp), tp2 = 1.f-2.f*sp, s2p = s1p*tp2;
    const float a01 = a0 + a1, p01 = p0 + p1;
    d[0] += a1 *(sa + a1 *(0.5f*s1a + 0.16666667f*a1 *s2a));
    d[1] += a0 *(sa + a0 *(0.5f*s1a + 0.16666667f*a0 *s2a));
    d[2] += a01*(sa + a01*(0.5f*s1a + 0.16666667f*a01*s2a));
    d[3] += p1 *(sp + p1 *(0.5f*s1p + 0.16666667f*p1 *s2p));
    d[4] += p0 *(sp + p0 *(0.5f*s1p + 0.16666667f*p0 *s2p));
    d[5] += p01*(sp + p01*(0.5f*s1p + 0.16666667f*p01*s2p));
    st_sa[i]=sa; st_sp[i]=sp; st_a0[i]=a0; st_a1[i]=a1; st_p0[i]=p0; st_p1[i]=p1;
  }

  __shared__ float red[6][4];
  __shared__ float lcr[4], lci[4];
  const int lane = t & 63, wv = t >> 6;
  #pragma unroll
  for (int i=0;i<6;i++){
    float x = d[i];
    for (int off=32; off>0; off>>=1) x += __shfl_down(x, off);
    if (lane==0) red[i][wv] = x;
  }
  __syncthreads();

  if (t==0){
    double ds[6];
    #pragma unroll
    for (int i=0;i<6;i++)
      ds[i] = (double)red[i][0]+red[i][1]+red[i][2]+red[i][3];

    const int bas0 = basis[(size_t)b*VN + t0], bas1 = basis[(size_t)b*VN + t1];
    const int x0 = (int)v0[(size_t)b*VN + t0], x1 = (int)v0[(size_t)b*VN + t1];
    const double A0 = vbA[t0], A1 = vbA[t1], P0 = vbP[t0], P1 = vbP[t1];

    double la[4], th[4];
    la[0]=0.0;                th[0]=0.0;
    la[1]=0.5*(A1+ds[0]);     th[1]=0.5*(P1+ds[3]);
    la[2]=0.5*(A0+ds[1]);     th[2]=0.5*(P0+ds[4]);
    la[3]=0.5*(A0+A1+ds[2]);  th[3]=0.5*(P0+P1+ds[5]);

    double wR[4], wI[4], sr=0.0, si=0.0;
    #pragma unroll
    for (int c=0;c<4;c++){
      const int s0 = (c>>1)&1, s1 = c&1;
      const float* u0 = unit + (((size_t)bas0*2 + x0)*2 + s0)*2;
      const float* u1 = unit + (((size_t)bas1*2 + x1)*2 + s1)*2;
      const double uR = (double)u0[0]*u1[0] - (double)u0[1]*u1[1];
      const double uI = (double)u0[0]*u1[1] + (double)u0[1]*u1[0];
      const double e  = exp(la[c]);
      const double cs = cos(th[c]), sn = sin(th[c]);
      wR[c] = e*(uR*cs - uI*sn);
      wI[c] = e*(uR*sn + uI*cs);
      sr += wR[c]; si += wI[c];
    }
    const double dd = sr*sr + si*si;
    #pragma unroll
    for (int c=0;c<4;c++){
      const float cr = (float)((wR[c]*sr + wI[c]*si)/dd);
      const float ci = (float)((wI[c]*sr - wR[c]*si)/dd);
      coefRe[b*4+c] = cr;  coefIm[b*4+c] = ci;
      lcr[c] = cr;         lci[c] = ci;
    }
    atomicAdd(tmpA + t0, lcr[2]+lcr[3]);
    atomicAdd(tmpA + t1, lcr[1]+lcr[3]);
    atomicAdd(tmpP + t0, lci[2]+lci[3]);
    atomicAdd(tmpP + t1, lci[1]+lci[3]);
  }
  __syncthreads();

  const float cr0=lcr[0], cr1=lcr[1], cr2=lcr[2], cr3=lcr[3];
  const float ci0=lci[0], ci1=lci[1], ci2=lci[2], ci3=lci[3];

  #pragma unroll
  for (int i = 0; i < 4; i++){
    const int h = t + i*256;
    const float sa = st_sa[i], sp = st_sp[i];
    const float a0 = st_a0[i], a1 = st_a1[i], p0 = st_p0[i], p1 = st_p1[i];
    const float s1a = sa*(1.f-sa), ta2 = 1.f-2.f*sa;
    const float s2a = s1a*ta2,     s3a = s1a*(ta2*ta2 - 2.f*s1a);
    const float s1p = sp*(1.f-sp), tp2 = 1.f-2.f*sp;
    const float s2p = s1p*tp2,     s3p = s1p*(tp2*tp2 - 2.f*s1p);
    const float a01 = a0 + a1, p01 = p0 + p1;
    const float sgA1 = sa + a1 *(s1a + a1 *(0.5f*s2a + 0.16666667f*a1 *s3a));
    const float sgA0 = sa + a0 *(s1a + a0 *(0.5f*s2a + 0.16666667f*a0 *s3a));
    const float sgA01= sa + a01*(s1a + a01*(0.5f*s2a + 0.16666667f*a01*s3a));
    const float sgP1 = sp + p1 *(s1p + p1 *(0.5f*s2p + 0.16666667f*p1 *s3p));
    const float sgP0 = sp + p0 *(s1p + p0 *(0.5f*s2p + 0.16666667f*p0 *s3p));
    const float sgP01= sp + p01*(s1p + p01*(0.5f*s2p + 0.16666667f*p01*s3p));
    Ramp[(size_t)b*HN + h] = cr0*sa + cr1*sgA1 + cr2*sgA0 + cr3*sgA01;
    Iph [(size_t)b*HN + h] = ci0*sp + ci1*sgP1 + ci2*sgP0 + ci3*sgP01;
  }
}

// ---------------------------------------------------------------------------
// CSR build + grouped tau-column scatter (bf16 operands, coalesced output)
// ---------------------------------------------------------------------------
__global__ void csr_count(const int* __restrict__ tau, int* __restrict__ cnt){
  int b = blockIdx.x*256 + threadIdx.x;
  atomicAdd(cnt + tau[2*b],   1);
  atomicAdd(cnt + tau[2*b+1], 1);
}

__global__ __launch_bounds__(1024) void csr_scan(const int* __restrict__ cnt,
                                                 int* __restrict__ off,
                                                 int* __restrict__ cur){
  __shared__ int s[1024];
  const int t = threadIdx.x;
  s[t] = cnt[t];
  __syncthreads();
  for (int d=1; d<1024; d<<=1){
    int v = 0;
    if (t >= d) v = s[t-d];
    __syncthreads();
    s[t] += v;
    __syncthreads();
  }
  const int excl = (t==0) ? 0 : s[t-1];
  off[t] = excl; cur[t] = excl;
}

__global__ void csr_fill(const int* __restrict__ tau, int* __restrict__ cur,
                         int* __restrict__ list){
  int b = blockIdx.x*256 + threadIdx.x;
  int p0 = atomicAdd(cur + tau[2*b],   1); list[p0] = b;
  int p1 = atomicAdd(cur + tau[2*b+1], 1); list[p1] = b;
}

// One block per v; thread handles 4 h's (ushort4 loads, float4 store).
// Writes COALESCED scratch gS[v][h] (the old gW[h][v] writes had 16x
// write amplification: 104MB for 8MB logical). bf16 operand reads halve
// fetch bytes; precision impact on gW ~1e-5 (INVB-scaled sigmoid terms).
__global__ __launch_bounds__(256) void scatter_v3(
    const unsigned short* __restrict__ pre0aBF,
    const unsigned short* __restrict__ pre0pBF,
    const unsigned short* __restrict__ WaTHi,
    const unsigned short* __restrict__ WpTHi,
    const int*   __restrict__ tau,
    const float* __restrict__ coefRe, const float* __restrict__ coefIm,
    const int* __restrict__ cnt, const int* __restrict__ off,
    const int* __restrict__ list,
    float* __restrict__ gSa, float* __restrict__ gSp)
{
  const int v  = blockIdx.x;
  const int h0 = threadIdx.x * 4;
  const int n  = cnt[v];
  const int o  = off[v];
  const int c_lo = (v < 512) ? 2 : 1;
  const bool lo_half = (v < 512);

  float accA[4] = {0,0,0,0}, accP[4] = {0,0,0,0};
  if (n > 0){
    const ushort4v avu = *(const ushort4v*)(WaTHi + (size_t)v*HN + h0);
    const ushort4v pvu = *(const ushort4v*)(WpTHi + (size_t)v*HN + h0);
    float av[4], pv[4];
    #pragma unroll
    for (int j=0;j<4;j++){ av[j]=bf2f(avu[j]); pv[j]=bf2f(pvu[j]); }
    for (int e = o; e < o + n; e++){
      const int b  = list[e];
      const int ot = lo_half ? tau[2*b+1] : tau[2*b];
      const ushort4v ao = *(const ushort4v*)(WaTHi  + (size_t)ot*HN + h0);
      const ushort4v po = *(const ushort4v*)(WpTHi  + (size_t)ot*HN + h0);
      const ushort4v pa = *(const ushort4v*)(pre0aBF + (size_t)b*HN + h0);
      const ushort4v pp = *(const ushort4v*)(pre0pBF + (size_t)b*HN + h0);
      const float crl = coefRe[b*4 + c_lo], cr3 = coefRe[b*4 + 3];
      const float cil = coefIm[b*4 + c_lo], ci3 = coefIm[b*4 + 3];
      #pragma unroll
      for (int j=0;j<4;j++){
        const float paf = bf2f(pa[j]) + av[j];
        const float ppf = bf2f(pp[j]) + pv[j];
        accA[j] += crl*sigmoidf(paf) + cr3*sigmoidf(paf + bf2f(ao[j]));
        accP[j] += cil*sigmoidf(ppf) + ci3*sigmoidf(ppf + bf2f(po[j]));
      }
    }
  }
  f32x4 ra, rp;
  #pragma unroll
  for (int j=0;j<4;j++){ ra[j]=accA[j]; rp[j]=accP[j]; }
  *(f32x4*)(gSa + (size_t)v*HN + h0) = ra;
  *(f32x4*)(gSp + (size_t)v*HN + h0) = rp;
}

// transpose-add: gWa[h][v] = -INVB*gSa[v][h]; gWp[h][v] = INVB*gSp[v][h].
// Plain store (=) -> replaces the out-zeroing pass; mfma_grad does += after.
__global__ void tadd_kernel(const float* __restrict__ gSa,
                            const float* __restrict__ gSp,
                            float* __restrict__ gWa,
                            float* __restrict__ gWp)
{
  __shared__ float ta[32][33], tp[32][33];
  const int tx = threadIdx.x, ty = threadIdx.y;   // (32,8)
  const int v0 = blockIdx.x*32, h0 = blockIdx.y*32;
  for (int j = ty; j < 32; j += 8){
    ta[j][tx] = gSa[(size_t)(v0+j)*HN + h0 + tx];
    tp[j][tx] = gSp[(size_t)(v0+j)*HN + h0 + tx];
  }
  __syncthreads();
  for (int j = ty; j < 32; j += 8){
    gWa[(size_t)(h0+j)*VN + v0 + tx] = -INVB*ta[tx][j];
    gWp[(size_t)(h0+j)*VN + v0 + tx] =  INVB*tp[tx][j];
  }
}

__global__ void final_small(
    const float* __restrict__ csV0m, const float* __restrict__ csVk,
    const float* __restrict__ csSigk, const float* __restrict__ csRamp,
    const float* __restrict__ csIph,
    const float* __restrict__ tmpA, const float* __restrict__ tmpP,
    float* __restrict__ gVa, float* __restrict__ gHa,
    float* __restrict__ gVp, float* __restrict__ gHp)
{
  const int j = blockIdx.x*256 + threadIdx.x;
  if (j < VN){
    gVa[j] = INVB*(csVk[j] - csV0m[j] - tmpA[j]);
    gVp[j] = INVB*tmpP[j];
  }
  if (j < HN){
    gHa[j] = INVB*(csSigk[j] - csRamp[j]);
    gHp[j] = INVB*csIph[j];
  }
}

// ---------------------------------------------------------------------------
extern "C" void kernel_launch(void* const* d_in, const int* in_sizes, int n_in,
                              void* d_out, int out_size, void* d_ws, size_t ws_size,
                              hipStream_t stream)
{
  const float* v0    = (const float*)d_in[0];
  const int*   basis = (const int*)  d_in[1];
  const int*   tau   = (const int*)  d_in[2];
  const float* unit  = (const float*)d_in[3];
  const float* Wa    = (const float*)d_in[4];
  const float* vbA   = (const float*)d_in[5];
  const float* hbA   = (const float*)d_in[6];
  const float* Wp    = (const float*)d_in[7];
  const float* vbP   = (const float*)d_in[8];
  const float* hbP   = (const float*)d_in[9];

  // workspace layout (~158 MB)
  float* ws    = (float*)d_ws;
  float* v0m   = ws;  ws += (size_t)BSZ*VN;
  float* v_cur = ws;  ws += (size_t)BSZ*VN;
  float* h_buf = ws;  ws += (size_t)BSZ*HN;   // pre0 bf16 copies, later sig_k
  float* WTa   = ws;  ws += (size_t)VN*HN;    // } dead after coef_ramp/scatter
  float* WTp   = ws;  ws += (size_t)VN*HN;    // }   -> sigkT (8MB)
  float* pre0a = ws;  ws += (size_t)BSZ*HN;   // -> gSa/gSp after coef_ramp,
  float* pre0p = ws;  ws += (size_t)BSZ*HN;   //    then v0mT/vkT, RampT/IphT
  float* Ramp  = ws;  ws += (size_t)BSZ*HN;
  float* Iph   = ws;  ws += (size_t)BSZ*HN;
  float* coefRe= ws;  ws += (size_t)BSZ*4;
  float* coefIm= ws;  ws += (size_t)BSZ*4;
  float* tmpA  = ws;  ws += VN;
  float* tmpP  = ws;  ws += VN;
  float* csV0m = ws;  ws += VN;
  float* csVk  = ws;  ws += VN;
  float* csSigk= ws;  ws += HN;
  float* csRamp= ws;  ws += HN;
  float* csIph = ws;  ws += HN;
  int*   csrCnt = (int*)ws;  ws += VN;
  int*   csrOff = (int*)ws;  ws += VN;
  int*   csrCur = (int*)ws;  ws += VN;
  int*   csrLst = (int*)ws;  ws += 2*BSZ;
  // bf16 buffers
  unsigned short* v_bf    = (unsigned short*)ws;  ws += (size_t)BSZ*VN/2;
  unsigned short* h_bf    = (unsigned short*)ws;  ws += (size_t)BSZ*HN/2;
  unsigned short* v0m_bf  = (unsigned short*)ws;  ws += (size_t)BSZ*VN/2;
  unsigned short* WaHi    = (unsigned short*)ws;  ws += (size_t)HN*VN/2;
  unsigned short* WaLo    = (unsigned short*)ws;  ws += (size_t)HN*VN/2;
  unsigned short* WpHi    = (unsigned short*)ws;  ws += (size_t)HN*VN/2;
  unsigned short* WpLo    = (unsigned short*)ws;  ws += (size_t)HN*VN/2;
  unsigned short* WaTHi   = (unsigned short*)ws;  ws += (size_t)HN*VN/2;
  unsigned short* WaTLo   = (unsigned short*)ws;  ws += (size_t)HN*VN/2;
  unsigned short* WpTHi   = (unsigned short*)ws;  ws += (size_t)HN*VN/2;

  float* sig_k = h_buf;
  // pre0 bf16 copies alias h_buf (free until sig_k at chain end; scatter
  // runs before the chain): 2 x 8 MB = h_buf's 16 MB exactly.
  unsigned short* pre0aBF = (unsigned short*)h_buf;
  unsigned short* pre0pBF = pre0aBF + (size_t)BSZ*HN;
  // scatter scratch aliases pre0a fp32 (dead after coef_ramp): 2 x 4 MB
  float* gSa = pre0a;
  float* gSp = pre0a + (size_t)VN*HN;
  // transposed bf16 gradient operands (phase 4), aliased into dead regions:
  unsigned short* v0mT  = (unsigned short*)pre0a;                  // 8 MB
  unsigned short* vkT   = v0mT + (size_t)VN*BSZ;                   // 8 MB
  unsigned short* RampT = (unsigned short*)pre0p;                  // 8 MB
  unsigned short* IphT  = RampT + (size_t)HN*BSZ;                  // 8 MB
  unsigned short* sigkT = (unsigned short*)WTa;                    // 8 MB

  float* out = (float*)d_out;
  float* gWa = out;
  float* gVa = gWa + (size_t)HN*VN;
  float* gHa = gVa + VN;
  float* gWp = gHa + HN;
  float* gVp = gWp + (size_t)HN*VN;
  float* gHp = gVp + VN;

  const dim3 gemm_grid(VN/GN, BSZ/GM);   // (16, 64) = 1024 wgs, 4/CU
  const dim3 tr_grid(1024/32, BSZ/32);   // (32, 128)
  const dim3 tr_blk(32, 8);

  // 1) init (out zeroing dropped: tadd writes gW with '=', final_small too)
  zero_kernel<<<dim3(40), 256, 0, stream>>>(tmpA, 10*1024);
  prep_kernel<<<dim3(BSZ*VN/256), 256, 0, stream>>>(v0, tau, v0m, v_cur, v0m_bf, v_bf);
  transpose_kernel<<<dim3(VN/32, HN/32, 2), dim3(32,8), 0, stream>>>(Wa, Wp, WTa, WTp);
  split_weights<<<dim3(HN*VN/256), 256, 0, stream>>>(
      Wa, Wp, WTa, WTp, WaHi, WaLo, WpHi, WpLo, WaTHi, WaTLo, WpTHi);

  // 2) positive phase: pre0 via MFMA (fp32 + bf16 copies), fused coef+ramp
  mfma_nt<3><<<gemm_grid, 256, 0, stream>>>(
      v0m_bf, WaHi, WaLo, hbA, pre0aBF, pre0a, 0u, 0u);
  mfma_nt<3><<<gemm_grid, 256, 0, stream>>>(
      v0m_bf, WpHi, WpLo, hbP, pre0pBF, pre0p, 0u, 0u);
  coef_ramp_kernel<<<dim3(BSZ), 256, 0, stream>>>(
      pre0a, pre0p, WTa, WTp, v0, vbA, vbP, tau, basis, unit,
      coefRe, coefIm, tmpA, tmpP, Ramp, Iph);

  // 2b) tau-column scatter: bf16 reads, coalesced gS writes, transpose-add
  csr_count<<<dim3(BSZ/256), 256, 0, stream>>>(tau, csrCnt);
  csr_scan <<<dim3(1), 1024, 0, stream>>>(csrCnt, csrOff, csrCur);
  csr_fill <<<dim3(BSZ/256), 256, 0, stream>>>(tau, csrCur, csrLst);
  scatter_v3<<<dim3(VN), 256, 0, stream>>>(
      pre0aBF, pre0pBF, WaTHi, WpTHi, tau, coefRe, coefIm,
      csrCnt, csrOff, csrLst, gSa, gSp);
  tadd_kernel<<<dim3(VN/32, HN/32), dim3(32,8), 0, stream>>>(
      gSa, gSp, gWa, gWp);

  // 3) CD-k Gibbs chain on matrix cores (bit-exact JAX partitionable
  //    threefry); fp32 v_cur written only at the LAST V-step
  for (int i = 0; i < NSTEPS; i++){
    unsigned kh0, kh1, kv0, kv1;
    tf2x32(0u, 1234u, 0u, (unsigned)(2*i),   kh0, kh1);
    tf2x32(0u, 1234u, 0u, (unsigned)(2*i+1), kv0, kv1);
    mfma_nt<0><<<gemm_grid, 256, 0, stream>>>(
        v_bf, WaHi, WaLo, hbA, h_bf, nullptr, kh0, kh1);
    if (i < NSTEPS-1)
      mfma_nt<0><<<gemm_grid, 256, 0, stream>>>(
          h_bf, WaTHi, WaTLo, vbA, v_bf, nullptr, kv0, kv1);
    else
      mfma_nt<1><<<gemm_grid, 256, 0, stream>>>(
          h_bf, WaTHi, WaTLo, vbA, v_bf, v_cur, kv0, kv1);
  }
  mfma_nt<2><<<gemm_grid, 256, 0, stream>>>(
      v_bf, WaHi, WaLo, hbA, nullptr, sig_k, 0u, 0u);

  // 4) transpose-convert gradient operands (with FUSED column sums),
  //    then MFMA gradient GEMMs
  transpose_to_bf<<<tr_grid, tr_blk, 0, stream>>>(v0m,   v0mT,  csV0m);
  transpose_to_bf<<<tr_grid, tr_blk, 0, stream>>>(v_cur, vkT,   csVk);
  transpose_to_bf<<<tr_grid, tr_blk, 0, stream>>>(Ramp,  RampT, csRamp);
  transpose_to_bf<<<tr_grid, tr_blk, 0, stream>>>(Iph,   IphT,  csIph);
  transpose_to_bf<<<tr_grid, tr_blk, 0, stream>>>(sig_k, sigkT, csSigk);

  mfma_grad<2><<<dim3(VN/64, HN/64), 256, 0, stream>>>(
      sigkT, vkT, RampT, v0mT, Wa, gWa);
  mfma_grad<1><<<dim3(VN/64, HN/64), 256, 0, stream>>>(
      IphT, v0mT, nullptr, nullptr, Wp, gWp);

  final_small<<<dim3(4), 256, 0, stream>>>(
      csV0m, csVk, csSigk, csRamp, csIph, tmpA, tmpP, gVa, gHa, gVp, gHp);
}

// Round 15
// 895.262 us; speedup vs baseline: 1.2758x; 1.0453x over previous
//
#include <hip/hip_runtime.h>
#include <cstdint>
#include <cstddef>

// Problem constants (fixed by the reference)
#define BSZ 4096
#define VN  1024
#define HN  1024
#define NSTEPS 10

static constexpr float INVB = 1.0f / 4096.0f;
static constexpr float L1R  = 1e-5f;
static constexpr float L2R  = 1e-4f;

typedef __attribute__((ext_vector_type(8)))  __bf16        bf16x8;
typedef __attribute__((ext_vector_type(8)))  unsigned short ushort8;
typedef __attribute__((ext_vector_type(4)))  unsigned short ushort4v;
typedef __attribute__((ext_vector_type(4)))  float          f32x4;
typedef __attribute__((ext_vector_type(16))) float          f32x16;

// ---------------------------------------------------------------------------
// bf16 helpers (RNE)
// ---------------------------------------------------------------------------
__device__ static inline unsigned short f2bf(float x){
  unsigned u = __float_as_uint(x);
  unsigned r = (u + 0x7FFFu + ((u >> 16) & 1u)) >> 16;
  return (unsigned short)r;
}
__device__ static inline float bf2f(unsigned short s){
  return __uint_as_float(((unsigned)s) << 16);
}

// async global->LDS, 16B per lane; LDS dest = wave-uniform base + lane*16
__device__ __forceinline__ void gload16(const void* g, void* l){
  __builtin_amdgcn_global_load_lds(
      (__attribute__((address_space(1))) void*)(g),
      (__attribute__((address_space(3))) void*)(l),
      16, 0, 0);
}

// ---------------------------------------------------------------------------
// Threefry-2x32 (bit-exact JAX PRNG)
// ---------------------------------------------------------------------------
#define TFR(x0,x1,r) { x0 += x1; x1 = ((x1)<<(r))|((x1)>>(32-(r))); x1 ^= x0; }

__host__ __device__ static inline void tf2x32(unsigned k0, unsigned k1,
                                              unsigned x0, unsigned x1,
                                              unsigned &o0, unsigned &o1)
{
  const unsigned ks2 = k0 ^ k1 ^ 0x1BD11BDAu;
  x0 += k0; x1 += k1;
  TFR(x0,x1,13) TFR(x0,x1,15) TFR(x0,x1,26) TFR(x0,x1,6)
  x0 += k1; x1 += ks2 + 1u;
  TFR(x0,x1,17) TFR(x0,x1,29) TFR(x0,x1,16) TFR(x0,x1,24)
  x0 += ks2; x1 += k0 + 2u;
  TFR(x0,x1,13) TFR(x0,x1,15) TFR(x0,x1,26) TFR(x0,x1,6)
  x0 += k0; x1 += k1 + 3u;
  TFR(x0,x1,17) TFR(x0,x1,29) TFR(x0,x1,16) TFR(x0,x1,24)
  x0 += k1; x1 += ks2 + 4u;
  TFR(x0,x1,13) TFR(x0,x1,15) TFR(x0,x1,26) TFR(x0,x1,6)
  x0 += ks2; x1 += k0 + 5u;
  o0 = x0; o1 = x1;
}

// jax.random.uniform element e — PARTITIONABLE threefry (JAX >= 0.4.30):
// counter (0, e); bits = xor-fold of the two outputs.
__device__ static inline float tf_uniform(unsigned k0, unsigned k1, unsigned e)
{
  unsigned o0, o1; tf2x32(k0, k1, 0u, e, o0, o1);
  const unsigned r = o0 ^ o1;
  return __uint_as_float((r >> 9) | 0x3f800000u) - 1.0f;
}

__device__ static inline float sigmoidf(float x){ return 1.0f/(1.0f+expf(-x)); }

// ---------------------------------------------------------------------------
// Small utility kernels
// ---------------------------------------------------------------------------
__global__ void zero_kernel(float* __restrict__ p, int n){
  int i = blockIdx.x*256 + threadIdx.x;
  if (i < n) p[i] = 0.0f;
}

// v0m = v0 with taus zeroed; v_cur=v0; bf16 copies for the MFMA path
__global__ void prep_kernel(const float* __restrict__ v0,
                            const int* __restrict__ tau,
                            float* __restrict__ v0m,
                            float* __restrict__ v_cur,
                            unsigned short* __restrict__ v0m_bf,
                            unsigned short* __restrict__ v_bf)
{
  int i = blockIdx.x*256 + threadIdx.x;     // exact grid BSZ*VN/256
  int b = i >> 10;
  int v = i & (VN-1);
  float x = v0[i];
  v_cur[i] = x;
  v_bf[i]  = f2bf(x);                        // 0/1 exact
  int t0 = tau[2*b], t1 = tau[2*b+1];
  float xm = (v==t0 || v==t1) ? 0.0f : x;
  v0m[i]    = xm;
  v0m_bf[i] = f2bf(xm);
}

// WT[v][h] = W[h][v] for both weight matrices (blockIdx.z selects)
__global__ void transpose_kernel(const float* __restrict__ Wa,
                                 const float* __restrict__ Wp,
                                 float* __restrict__ WTa,
                                 float* __restrict__ WTp)
{
  __shared__ float tile[32][33];
  const float* in = blockIdx.z ? Wp : Wa;
  float* out      = blockIdx.z ? WTp : WTa;
  int x  = blockIdx.x*32 + threadIdx.x;
  int y0 = blockIdx.y*32;
  for (int j = threadIdx.y; j < 32; j += 8)
    tile[j][threadIdx.x] = in[(size_t)(y0+j)*VN + x];
  __syncthreads();
  int xo  = y0 + threadIdx.x;
  int yo0 = blockIdx.x*32;
  for (int j = threadIdx.y; j < 32; j += 8)
    out[(size_t)(yo0+j)*HN + xo] = tile[threadIdx.x][j];
}

// transpose fp32 [BSZ][1024] -> bf16 (RNE) [1024][BSZ], FUSED column sum
__global__ void transpose_to_bf(const float* __restrict__ X,
                                unsigned short* __restrict__ XT,
                                float* __restrict__ cs)
{
  __shared__ float tile[32][33];
  const int tx = threadIdx.x, ty = threadIdx.y;
  int x  = blockIdx.x*32 + tx;            // col 0..1023
  int y0 = blockIdx.y*32;                 // row base 0..4095
  for (int j = ty; j < 32; j += 8)
    tile[j][tx] = X[(size_t)(y0+j)*1024 + x];
  __syncthreads();
  int xo  = y0 + tx;                      // b index in output row
  int yo0 = blockIdx.x*32;                // output row
  for (int j = ty; j < 32; j += 8)
    XT[(size_t)(yo0+j)*BSZ + xo] = f2bf(tile[tx][j]);
  float s = tile[ty][tx] + tile[ty+8][tx] + tile[ty+16][tx] + tile[ty+24][tx];
  __syncthreads();
  tile[ty][tx] = s;
  __syncthreads();
  if (ty == 0){
    float t = 0.f;
    #pragma unroll
    for (int j = 0; j < 8; j++) t += tile[j][tx];
    atomicAdd(cs + x, t);
  }
}

// hi/lo bf16 split of Wa, Wp, Wa^T; hi-only of Wp^T (for bf16 scatter)
__global__ void split_weights(const float* __restrict__ Wa,
                              const float* __restrict__ Wp,
                              const float* __restrict__ WTa,
                              const float* __restrict__ WTp,
                              unsigned short* __restrict__ WaHi,
                              unsigned short* __restrict__ WaLo,
                              unsigned short* __restrict__ WpHi,
                              unsigned short* __restrict__ WpLo,
                              unsigned short* __restrict__ WaTHi,
                              unsigned short* __restrict__ WaTLo,
                              unsigned short* __restrict__ WpTHi)
{
  size_t i = (size_t)blockIdx.x*256 + threadIdx.x;   // grid HN*VN/256
  float w = Wa[i];  unsigned short h = f2bf(w);
  WaHi[i] = h;  WaLo[i] = f2bf(w - bf2f(h));
  w = Wp[i];  h = f2bf(w);
  WpHi[i] = h;  WpLo[i] = f2bf(w - bf2f(h));
  w = WTa[i]; h = f2bf(w);
  WaTHi[i] = h; WaTLo[i] = f2bf(w - bf2f(h));
  WpTHi[i] = f2bf(WTp[i]);
}

// ---------------------------------------------------------------------------
// MFMA NT GEMM with hi/lo bf16 split B and fused epilogue (R12/R14 form).
// Tile 64x64, BK=64; 4 waves as 2x2 grid of 32x32 sub-tiles; 4 blocks/CU.
// K-accumulation order fixed -> bit-identical samples across rounds.
// MODE 0: sample -> bf16 out        (Gibbs H-step / V-steps 0..8)
// MODE 1: sample -> bf16 + fp32 out (last V-step)
// MODE 2: sigmoid -> fp32           (sig_k)
// MODE 3: raw pre -> fp32 + bf16    (pre0a / pre0p; bf16 copy for scatter)
// ---------------------------------------------------------------------------
#define GM 64
#define GN 64
#define GK 64

template<int MODE>
__global__ __launch_bounds__(256) void mfma_nt(
    const unsigned short* __restrict__ A,     // [M][1024] bf16 (binary)
    const unsigned short* __restrict__ Bhi,   // [N][1024] bf16
    const unsigned short* __restrict__ Blo,   // [N][1024] bf16
    const float* __restrict__ bias,           // [N]
    unsigned short* __restrict__ out_bf,      // MODE 0,1,3
    float* __restrict__ out_f,                // MODE 1,2,3
    unsigned key0, unsigned key1)
{
  constexpr int K = 1024;
  constexpr int N = 1024;
  __shared__ ushort8 ldsA [GM*8];     // 8 KB
  __shared__ ushort8 ldsBh[GN*8];     // 8 KB
  __shared__ ushort8 ldsBl[GN*8];     // 8 KB

  // XCD-bijective swizzle: 1024 wgs / 8 XCDs = 128 contiguous per XCD
  const int orig = blockIdx.x + gridDim.x * blockIdx.y;
  const int swz  = (orig & 7) * 128 + (orig >> 3);
  const int bx   = swz & 15, by = swz >> 4;
  const int m0   = by*GM, n0 = bx*GN;

  const int tid  = threadIdx.x;
  const int lane = tid & 63, w = tid >> 6;
  const int wm = w >> 1, wn = w & 1;       // 2x2 wave grid over 32x32 tiles
  const int l31 = lane & 31, hi = lane >> 5;
  const int rsub = lane >> 3;         // 0..7
  const int cch  = lane & 7;          // chunk 0..7

  f32x16 acc = {};

  const int arow = wm*32 + l31;       // wave's 32-row A band   (0..63)
  const int brow = wn*32 + l31;       // wave's 32-row B band   (0..63)
  const int aswz = arow & 7;
  const int bswz = brow & 7;
  const int aidx = arow*8;
  const int bidx = brow*8;

  for (int kt = 0; kt < K/GK; ++kt){
    __syncthreads();
    const size_t kbase = (size_t)kt*GK;
    #pragma unroll
    for (int p = 0; p < 2; p++){
      const int row  = p*32 + w*8 + rsub;
      const int csrc = cch ^ (row & 7);
      gload16(A   + (size_t)(m0+row)*K + kbase + csrc*8, &ldsA [(p*32 + w*8)*8]);
      gload16(Bhi + (size_t)(n0+row)*K + kbase + csrc*8, &ldsBh[(p*32 + w*8)*8]);
      gload16(Blo + (size_t)(n0+row)*K + kbase + csrc*8, &ldsBl[(p*32 + w*8)*8]);
    }
    __syncthreads();   // drains vmcnt before barrier (compiler-inserted)

    #pragma unroll
    for (int s = 0; s < 4; s++){
      const int c = s*2 + hi;
      const bf16x8 a  = __builtin_bit_cast(bf16x8, ldsA [aidx + (c ^ aswz)]);
      const bf16x8 bh = __builtin_bit_cast(bf16x8, ldsBh[bidx + (c ^ bswz)]);
      const bf16x8 bl = __builtin_bit_cast(bf16x8, ldsBl[bidx + (c ^ bswz)]);
      acc = __builtin_amdgcn_mfma_f32_32x32x16_bf16(a, bh, acc, 0, 0, 0);
      acc = __builtin_amdgcn_mfma_f32_32x32x16_bf16(a, bl, acc, 0, 0, 0);
    }
  }

  // epilogue: C/D layout col=lane&31, row=(reg&3)+8*(reg>>2)+4*(lane>>5)
  const int n  = n0 + wn*32 + l31;
  const float bv = bias[n];
  const int mbase = m0 + wm*32 + 4*hi;
  #pragma unroll
  for (int r = 0; r < 16; r++){
    const int m = mbase + (r&3) + 8*(r>>2);
    const float pre = acc[r] + bv;
    const size_t o = (size_t)m*N + n;
    if constexpr (MODE == 0 || MODE == 1){
      const float p = sigmoidf(pre);
      const float u = tf_uniform(key0, key1, (unsigned)(m*N + n));
      out_bf[o] = (u < p) ? (unsigned short)0x3F80 : (unsigned short)0;
      if constexpr (MODE == 1) out_f[o] = (u < p) ? 1.0f : 0.0f;
    } else if constexpr (MODE == 2){
      out_f[o] = sigmoidf(pre);
    } else {
      out_f[o]  = pre;
      out_bf[o] = f2bf(pre);
    }
  }
}

// ---------------------------------------------------------------------------
// Split-K MFMA gradient GEMM (NT over transposed operands, K-slice 1024).
// grid (16,16,4) = 1024 blocks = 4/CU (fixes R14's 1-blk/CU occupancy AND
// the 4.2M ds_write bank conflicts: gload16 staging, pre-swizzled source).
// NPROD==2: part[z] = A1*B1^T - A2*B2^T   NPROD==1: part[z] = A1*B1^T
// ---------------------------------------------------------------------------
template<int NPROD>
__global__ __launch_bounds__(256) void mfma_grad_split(
    const unsigned short* __restrict__ A1,   // [1024][4096] bf16
    const unsigned short* __restrict__ B1,   // [1024][4096] bf16
    const unsigned short* __restrict__ A2,
    const unsigned short* __restrict__ B2,
    float* __restrict__ part)                // [4][HN][VN]
{
  constexpr int K = BSZ;
  __shared__ ushort8 lA1[64*8];
  __shared__ ushort8 lB1[64*8];
  __shared__ ushort8 lA2[(NPROD==2)?64*8:1];
  __shared__ ushort8 lB2[(NPROD==2)?64*8:1];

  const int tid  = threadIdx.x;
  const int m0   = blockIdx.y*64, n0 = blockIdx.x*64;
  const int kz   = blockIdx.z;                      // 0..3
  const int lane = tid & 63, w = tid >> 6;
  const int wm = w >> 1, wn = w & 1;
  const int l31 = lane & 31, hi = lane >> 5;
  const int rsub = lane >> 3;
  const int cch  = lane & 7;

  f32x16 acc1a = {}, acc1b = {}, acc2a = {}, acc2b = {};

  const int arow = wm*32 + l31;
  const int brow = wn*32 + l31;
  const int aswz = arow & 7, bswz = brow & 7;
  const int aidx = arow*8,  bidx = brow*8;

  for (int kt = 0; kt < 16; ++kt){
    __syncthreads();
    const size_t kbase = (size_t)kz*1024 + (size_t)kt*64;
    #pragma unroll
    for (int p = 0; p < 2; p++){
      const int row  = p*32 + w*8 + rsub;
      const int csrc = cch ^ (row & 7);
      gload16(A1 + (size_t)(m0+row)*K + kbase + csrc*8, &lA1[(p*32 + w*8)*8]);
      gload16(B1 + (size_t)(n0+row)*K + kbase + csrc*8, &lB1[(p*32 + w*8)*8]);
      if constexpr (NPROD==2){
        gload16(A2 + (size_t)(m0+row)*K + kbase + csrc*8, &lA2[(p*32 + w*8)*8]);
        gload16(B2 + (size_t)(n0+row)*K + kbase + csrc*8, &lB2[(p*32 + w*8)*8]);
      }
    }
    __syncthreads();
    #pragma unroll
    for (int s = 0; s < 4; s++){
      const int c = s*2 + hi;
      const bf16x8 a1 = __builtin_bit_cast(bf16x8, lA1[aidx + (c ^ aswz)]);
      const bf16x8 b1 = __builtin_bit_cast(bf16x8, lB1[bidx + (c ^ bswz)]);
      if (s & 1) acc1b = __builtin_amdgcn_mfma_f32_32x32x16_bf16(a1, b1, acc1b, 0,0,0);
      else       acc1a = __builtin_amdgcn_mfma_f32_32x32x16_bf16(a1, b1, acc1a, 0,0,0);
      if constexpr (NPROD==2){
        const bf16x8 a2 = __builtin_bit_cast(bf16x8, lA2[aidx + (c ^ aswz)]);
        const bf16x8 b2 = __builtin_bit_cast(bf16x8, lB2[bidx + (c ^ bswz)]);
        if (s & 1) acc2b = __builtin_amdgcn_mfma_f32_32x32x16_bf16(a2, b2, acc2b, 0,0,0);
        else       acc2a = __builtin_amdgcn_mfma_f32_32x32x16_bf16(a2, b2, acc2a, 0,0,0);
      }
    }
  }

  float* outp = part + (size_t)kz * HN * VN;
  const int n = n0 + wn*32 + l31;
  #pragma unroll
  for (int r = 0; r < 16; r++){
    const int m = m0 + wm*32 + 4*hi + (r&3) + 8*(r>>2);
    const size_t o = (size_t)m*VN + n;
    if constexpr (NPROD==2)
      outp[o] = (acc1a[r]+acc1b[r]) - (acc2a[r]+acc2b[r]);
    else
      outp[o] = acc1a[r]+acc1b[r];
  }
}

// finalize: gW += INVB*sum_z(part) + L2*W + L1*sign(W)   (both matrices)
__global__ __launch_bounds__(256) void finalize_grad(
    const float* __restrict__ partA, const float* __restrict__ partP,
    const float* __restrict__ Wa,    const float* __restrict__ Wp,
    float* __restrict__ gWa, float* __restrict__ gWp)
{
  const size_t i  = (size_t)blockIdx.x*256 + threadIdx.x;
  const size_t MN = (size_t)HN*VN;
  const float sA = ((partA[i] + partA[MN+i]) + partA[2*MN+i]) + partA[3*MN+i];
  const float sP = ((partP[i] + partP[MN+i]) + partP[2*MN+i]) + partP[3*MN+i];
  const float wa = Wa[i], wp = Wp[i];
  const float sga = (wa>0.f)?1.f:((wa<0.f)?-1.f:0.f);
  const float sgp = (wp>0.f)?1.f:((wp<0.f)?-1.f:0.f);
  gWa[i] += INVB*sA + L2R*wa + L1R*sga;
  gWp[i] += INVB*sP + L2R*wp + L1R*sgp;
}

// ---------------------------------------------------------------------------
// Fused coef + ramp kernel (Taylor-3 differentials + fp64 tail; see R7)
// ---------------------------------------------------------------------------
__global__ __launch_bounds__(256) void coef_ramp_kernel(
    const float* __restrict__ pre0a, const float* __restrict__ pre0p,
    const float* __restrict__ WTa,   const float* __restrict__ WTp,
    const float* __restrict__ v0,
    const float* __restrict__ vbA,   const float* __restrict__ vbP,
    const int*   __restrict__ tau,   const int*   __restrict__ basis,
    const float* __restrict__ unit,
    float* __restrict__ coefRe, float* __restrict__ coefIm,
    float* __restrict__ tmpA,   float* __restrict__ tmpP,
    float* __restrict__ Ramp,   float* __restrict__ Iph)
{
  const int b = blockIdx.x;
  const int t = threadIdx.x;
  const int t0 = tau[2*b], t1 = tau[2*b+1];

  float d[6] = {0,0,0,0,0,0};
  float st_sa[4], st_sp[4], st_a0[4], st_a1[4], st_p0[4], st_p1[4];

  #pragma unroll
  for (int i = 0; i < 4; i++){
    const int h = t + i*256;
    const float pa = pre0a[(size_t)b*HN + h], pp = pre0p[(size_t)b*HN + h];
    const float a0 = WTa[(size_t)t0*HN + h], a1 = WTa[(size_t)t1*HN + h];
    const float p0 = WTp[(size_t)t0*HN + h], p1 = WTp[(size_t)t1*HN + h];
    const float sa  = sigmoidf(pa);
    const float sp  = sigmoidf(pp);
    const float s1a = sa*(1.f-sa), ta2 = 1.f-2.f*sa, s2a = s1a*ta2;
    const float s1p = sp*(1.f-sp), tp2 = 1.f-2.f*sp, s2p = s1p*tp2;
    const float a01 = a0 + a1, p01 = p0 + p1;
    d[0] += a1 *(sa + a1 *(0.5f*s1a + 0.16666667f*a1 *s2a));
    d[1] += a0 *(sa + a0 *(0.5f*s1a + 0.16666667f*a0 *s2a));
    d[2] += a01*(sa + a01*(0.5f*s1a + 0.16666667f*a01*s2a));
    d[3] += p1 *(sp + p1 *(0.5f*s1p + 0.16666667f*p1 *s2p));
    d[4] += p0 *(sp + p0 *(0.5f*s1p + 0.16666667f*p0 *s2p));
    d[5] += p01*(sp + p01*(0.5f*s1p + 0.16666667f*p01*s2p));
    st_sa[i]=sa; st_sp[i]=sp; st_a0[i]=a0; st_a1[i]=a1; st_p0[i]=p0; st_p1[i]=p1;
  }

  __shared__ float red[6][4];
  __shared__ float lcr[4], lci[4];
  const int lane = t & 63, wv = t >> 6;
  #pragma unroll
  for (int i=0;i<6;i++){
    float x = d[i];
    for (int off=32; off>0; off>>=1) x += __shfl_down(x, off);
    if (lane==0) red[i][wv] = x;
  }
  __syncthreads();

  if (t==0){
    double ds[6];
    #pragma unroll
    for (int i=0;i<6;i++)
      ds[i] = (double)red[i][0]+red[i][1]+red[i][2]+red[i][3];

    const int bas0 = basis[(size_t)b*VN + t0], bas1 = basis[(size_t)b*VN + t1];
    const int x0 = (int)v0[(size_t)b*VN + t0], x1 = (int)v0[(size_t)b*VN + t1];
    const double A0 = vbA[t0], A1 = vbA[t1], P0 = vbP[t0], P1 = vbP[t1];

    double la[4], th[4];
    la[0]=0.0;                th[0]=0.0;
    la[1]=0.5*(A1+ds[0]);     th[1]=0.5*(P1+ds[3]);
    la[2]=0.5*(A0+ds[1]);     th[2]=0.5*(P0+ds[4]);
    la[3]=0.5*(A0+A1+ds[2]);  th[3]=0.5*(P0+P1+ds[5]);

    double wR[4], wI[4], sr=0.0, si=0.0;
    #pragma unroll
    for (int c=0;c<4;c++){
      const int s0 = (c>>1)&1, s1 = c&1;
      const float* u0 = unit + (((size_t)bas0*2 + x0)*2 + s0)*2;
      const float* u1 = unit + (((size_t)bas1*2 + x1)*2 + s1)*2;
      const double uR = (double)u0[0]*u1[0] - (double)u0[1]*u1[1];
      const double uI = (double)u0[0]*u1[1] + (double)u0[1]*u1[0];
      const double e  = exp(la[c]);
      const double cs = cos(th[c]), sn = sin(th[c]);
      wR[c] = e*(uR*cs - uI*sn);
      wI[c] = e*(uR*sn + uI*cs);
      sr += wR[c]; si += wI[c];
    }
    const double dd = sr*sr + si*si;
    #pragma unroll
    for (int c=0;c<4;c++){
      const float cr = (float)((wR[c]*sr + wI[c]*si)/dd);
      const float ci = (float)((wI[c]*sr - wR[c]*si)/dd);
      coefRe[b*4+c] = cr;  coefIm[b*4+c] = ci;
      lcr[c] = cr;         lci[c] = ci;
    }
    atomicAdd(tmpA + t0, lcr[2]+lcr[3]);
    atomicAdd(tmpA + t1, lcr[1]+lcr[3]);
    atomicAdd(tmpP + t0, lci[2]+lci[3]);
    atomicAdd(tmpP + t1, lci[1]+lci[3]);
  }
  __syncthreads();

  const float cr0=lcr[0], cr1=lcr[1], cr2=lcr[2], cr3=lcr[3];
  const float ci0=lci[0], ci1=lci[1], ci2=lci[2], ci3=lci[3];

  #pragma unroll
  for (int i = 0; i < 4; i++){
    const int h = t + i*256;
    const float sa = st_sa[i], sp = st_sp[i];
    const float a0 = st_a0[i], a1 = st_a1[i], p0 = st_p0[i], p1 = st_p1[i];
    const float s1a = sa*(1.f-sa), ta2 = 1.f-2.f*sa;
    const float s2a = s1a*ta2,     s3a = s1a*(ta2*ta2 - 2.f*s1a);
    const float s1p = sp*(1.f-sp), tp2 = 1.f-2.f*sp;
    const float s2p = s1p*tp2,     s3p = s1p*(tp2*tp2 - 2.f*s1p);
    const float a01 = a0 + a1, p01 = p0 + p1;
    const float sgA1 = sa + a1 *(s1a + a1 *(0.5f*s2a + 0.16666667f*a1 *s3a));
    const float sgA0 = sa + a0 *(s1a + a0 *(0.5f*s2a + 0.16666667f*a0 *s3a));
    const float sgA01= sa + a01*(s1a + a01*(0.5f*s2a + 0.16666667f*a01*s3a));
    const float sgP1 = sp + p1 *(s1p + p1 *(0.5f*s2p + 0.16666667f*p1 *s3p));
    const float sgP0 = sp + p0 *(s1p + p0 *(0.5f*s2p + 0.16666667f*p0 *s3p));
    const float sgP01= sp + p01*(s1p + p01*(0.5f*s2p + 0.16666667f*p01*s3p));
    Ramp[(size_t)b*HN + h] = cr0*sa + cr1*sgA1 + cr2*sgA0 + cr3*sgA01;
    Iph [(size_t)b*HN + h] = ci0*sp + ci1*sgP1 + ci2*sgP0 + ci3*sgP01;
  }
}

// ---------------------------------------------------------------------------
// CSR build + grouped tau-column scatter (bf16 operands, coalesced output)
// ---------------------------------------------------------------------------
__global__ void csr_count(const int* __restrict__ tau, int* __restrict__ cnt){
  int b = blockIdx.x*256 + threadIdx.x;
  atomicAdd(cnt + tau[2*b],   1);
  atomicAdd(cnt + tau[2*b+1], 1);
}

__global__ __launch_bounds__(1024) void csr_scan(const int* __restrict__ cnt,
                                                 int* __restrict__ off,
                                                 int* __restrict__ cur){
  __shared__ int s[1024];
  const int t = threadIdx.x;
  s[t] = cnt[t];
  __syncthreads();
  for (int d=1; d<1024; d<<=1){
    int v = 0;
    if (t >= d) v = s[t-d];
    __syncthreads();
    s[t] += v;
    __syncthreads();
  }
  const int excl = (t==0) ? 0 : s[t-1];
  off[t] = excl; cur[t] = excl;
}

__global__ void csr_fill(const int* __restrict__ tau, int* __restrict__ cur,
                         int* __restrict__ list){
  int b = blockIdx.x*256 + threadIdx.x;
  int p0 = atomicAdd(cur + tau[2*b],   1); list[p0] = b;
  int p1 = atomicAdd(cur + tau[2*b+1], 1); list[p1] = b;
}

// One block per v; thread handles 4 h's (ushort4 loads, float4 store).
__global__ __launch_bounds__(256) void scatter_v3(
    const unsigned short* __restrict__ pre0aBF,
    const unsigned short* __restrict__ pre0pBF,
    const unsigned short* __restrict__ WaTHi,
    const unsigned short* __restrict__ WpTHi,
    const int*   __restrict__ tau,
    const float* __restrict__ coefRe, const float* __restrict__ coefIm,
    const int* __restrict__ cnt, const int* __restrict__ off,
    const int* __restrict__ list,
    float* __restrict__ gSa, float* __restrict__ gSp)
{
  const int v  = blockIdx.x;
  const int h0 = threadIdx.x * 4;
  const int n  = cnt[v];
  const int o  = off[v];
  const int c_lo = (v < 512) ? 2 : 1;
  const bool lo_half = (v < 512);

  float accA[4] = {0,0,0,0}, accP[4] = {0,0,0,0};
  if (n > 0){
    const ushort4v avu = *(const ushort4v*)(WaTHi + (size_t)v*HN + h0);
    const ushort4v pvu = *(const ushort4v*)(WpTHi + (size_t)v*HN + h0);
    float av[4], pv[4];
    #pragma unroll
    for (int j=0;j<4;j++){ av[j]=bf2f(avu[j]); pv[j]=bf2f(pvu[j]); }
    for (int e = o; e < o + n; e++){
      const int b  = list[e];
      const int ot = lo_half ? tau[2*b+1] : tau[2*b];
      const ushort4v ao = *(const ushort4v*)(WaTHi  + (size_t)ot*HN + h0);
      const ushort4v po = *(const ushort4v*)(WpTHi  + (size_t)ot*HN + h0);
      const ushort4v pa = *(const ushort4v*)(pre0aBF + (size_t)b*HN + h0);
      const ushort4v pp = *(const ushort4v*)(pre0pBF + (size_t)b*HN + h0);
      const float crl = coefRe[b*4 + c_lo], cr3 = coefRe[b*4 + 3];
      const float cil = coefIm[b*4 + c_lo], ci3 = coefIm[b*4 + 3];
      #pragma unroll
      for (int j=0;j<4;j++){
        const float paf = bf2f(pa[j]) + av[j];
        const float ppf = bf2f(pp[j]) + pv[j];
        accA[j] += crl*sigmoidf(paf) + cr3*sigmoidf(paf + bf2f(ao[j]));
        accP[j] += cil*sigmoidf(ppf) + ci3*sigmoidf(ppf + bf2f(po[j]));
      }
    }
  }
  f32x4 ra, rp;
  #pragma unroll
  for (int j=0;j<4;j++){ ra[j]=accA[j]; rp[j]=accP[j]; }
  *(f32x4*)(gSa + (size_t)v*HN + h0) = ra;
  *(f32x4*)(gSp + (size_t)v*HN + h0) = rp;
}

// transpose-add: gWa[h][v] = -INVB*gSa[v][h]; gWp[h][v] = INVB*gSp[v][h].
__global__ void tadd_kernel(const float* __restrict__ gSa,
                            const float* __restrict__ gSp,
                            float* __restrict__ gWa,
                            float* __restrict__ gWp)
{
  __shared__ float ta[32][33], tp[32][33];
  const int tx = threadIdx.x, ty = threadIdx.y;   // (32,8)
  const int v0 = blockIdx.x*32, h0 = blockIdx.y*32;
  for (int j = ty; j < 32; j += 8){
    ta[j][tx] = gSa[(size_t)(v0+j)*HN + h0 + tx];
    tp[j][tx] = gSp[(size_t)(v0+j)*HN + h0 + tx];
  }
  __syncthreads();
  for (int j = ty; j < 32; j += 8){
    gWa[(size_t)(h0+j)*VN + v0 + tx] = -INVB*ta[tx][j];
    gWp[(size_t)(h0+j)*VN + v0 + tx] =  INVB*tp[tx][j];
  }
}

__global__ void final_small(
    const float* __restrict__ csV0m, const float* __restrict__ csVk,
    const float* __restrict__ csSigk, const float* __restrict__ csRamp,
    const float* __restrict__ csIph,
    const float* __restrict__ tmpA, const float* __restrict__ tmpP,
    float* __restrict__ gVa, float* __restrict__ gHa,
    float* __restrict__ gVp, float* __restrict__ gHp)
{
  const int j = blockIdx.x*256 + threadIdx.x;
  if (j < VN){
    gVa[j] = INVB*(csVk[j] - csV0m[j] - tmpA[j]);
    gVp[j] = INVB*tmpP[j];
  }
  if (j < HN){
    gHa[j] = INVB*(csSigk[j] - csRamp[j]);
    gHp[j] = INVB*csIph[j];
  }
}

// ---------------------------------------------------------------------------
extern "C" void kernel_launch(void* const* d_in, const int* in_sizes, int n_in,
                              void* d_out, int out_size, void* d_ws, size_t ws_size,
                              hipStream_t stream)
{
  const float* v0    = (const float*)d_in[0];
  const int*   basis = (const int*)  d_in[1];
  const int*   tau   = (const int*)  d_in[2];
  const float* unit  = (const float*)d_in[3];
  const float* Wa    = (const float*)d_in[4];
  const float* vbA   = (const float*)d_in[5];
  const float* hbA   = (const float*)d_in[6];
  const float* Wp    = (const float*)d_in[7];
  const float* vbP   = (const float*)d_in[8];
  const float* hbP   = (const float*)d_in[9];

  // workspace layout (~158 MB)
  float* ws    = (float*)d_ws;
  float* v0m   = ws;  ws += (size_t)BSZ*VN;   // -> partA after transpose_to_bf
  float* v_cur = ws;  ws += (size_t)BSZ*VN;   // -> partP after transpose_to_bf
  float* h_buf = ws;  ws += (size_t)BSZ*HN;   // pre0 bf16 copies, later sig_k
  float* WTa   = ws;  ws += (size_t)VN*HN;    // } dead after coef_ramp/scatter
  float* WTp   = ws;  ws += (size_t)VN*HN;    // }   -> sigkT (8MB)
  float* pre0a = ws;  ws += (size_t)BSZ*HN;   // -> gSa/gSp, then v0mT/vkT
  float* pre0p = ws;  ws += (size_t)BSZ*HN;   // -> RampT/IphT
  float* Ramp  = ws;  ws += (size_t)BSZ*HN;
  float* Iph   = ws;  ws += (size_t)BSZ*HN;
  float* coefRe= ws;  ws += (size_t)BSZ*4;
  float* coefIm= ws;  ws += (size_t)BSZ*4;
  float* tmpA  = ws;  ws += VN;
  float* tmpP  = ws;  ws += VN;
  float* csV0m = ws;  ws += VN;
  float* csVk  = ws;  ws += VN;
  float* csSigk= ws;  ws += HN;
  float* csRamp= ws;  ws += HN;
  float* csIph = ws;  ws += HN;
  int*   csrCnt = (int*)ws;  ws += VN;
  int*   csrOff = (int*)ws;  ws += VN;
  int*   csrCur = (int*)ws;  ws += VN;
  int*   csrLst = (int*)ws;  ws += 2*BSZ;
  // bf16 buffers
  unsigned short* v_bf    = (unsigned short*)ws;  ws += (size_t)BSZ*VN/2;
  unsigned short* h_bf    = (unsigned short*)ws;  ws += (size_t)BSZ*HN/2;
  unsigned short* v0m_bf  = (unsigned short*)ws;  ws += (size_t)BSZ*VN/2;
  unsigned short* WaHi    = (unsigned short*)ws;  ws += (size_t)HN*VN/2;
  unsigned short* WaLo    = (unsigned short*)ws;  ws += (size_t)HN*VN/2;
  unsigned short* WpHi    = (unsigned short*)ws;  ws += (size_t)HN*VN/2;
  unsigned short* WpLo    = (unsigned short*)ws;  ws += (size_t)HN*VN/2;
  unsigned short* WaTHi   = (unsigned short*)ws;  ws += (size_t)HN*VN/2;
  unsigned short* WaTLo   = (unsigned short*)ws;  ws += (size_t)HN*VN/2;
  unsigned short* WpTHi   = (unsigned short*)ws;  ws += (size_t)HN*VN/2;

  float* sig_k = h_buf;
  unsigned short* pre0aBF = (unsigned short*)h_buf;
  unsigned short* pre0pBF = pre0aBF + (size_t)BSZ*HN;
  float* gSa = pre0a;
  float* gSp = pre0a + (size_t)VN*HN;
  unsigned short* v0mT  = (unsigned short*)pre0a;                  // 8 MB
  unsigned short* vkT   = v0mT + (size_t)VN*BSZ;                   // 8 MB
  unsigned short* RampT = (unsigned short*)pre0p;                  // 8 MB
  unsigned short* IphT  = RampT + (size_t)HN*BSZ;                  // 8 MB
  unsigned short* sigkT = (unsigned short*)WTa;                    // 8 MB
  float* partA = v0m;                          // [4][HN][VN] = 16 MB
  float* partP = v_cur;                        // [4][HN][VN] = 16 MB

  float* out = (float*)d_out;
  float* gWa = out;
  float* gVa = gWa + (size_t)HN*VN;
  float* gHa = gVa + VN;
  float* gWp = gHa + HN;
  float* gVp = gWp + (size_t)HN*VN;
  float* gHp = gVp + VN;

  const dim3 gemm_grid(VN/GN, BSZ/GM);   // (16, 64) = 1024 wgs, 4/CU
  const dim3 tr_grid(1024/32, BSZ/32);   // (32, 128)
  const dim3 tr_blk(32, 8);

  // 1) init
  zero_kernel<<<dim3(40), 256, 0, stream>>>(tmpA, 10*1024);
  prep_kernel<<<dim3(BSZ*VN/256), 256, 0, stream>>>(v0, tau, v0m, v_cur, v0m_bf, v_bf);
  transpose_kernel<<<dim3(VN/32, HN/32, 2), dim3(32,8), 0, stream>>>(Wa, Wp, WTa, WTp);
  split_weights<<<dim3(HN*VN/256), 256, 0, stream>>>(
      Wa, Wp, WTa, WTp, WaHi, WaLo, WpHi, WpLo, WaTHi, WaTLo, WpTHi);

  // 2) positive phase: pre0 via MFMA (fp32 + bf16 copies), fused coef+ramp
  mfma_nt<3><<<gemm_grid, 256, 0, stream>>>(
      v0m_bf, WaHi, WaLo, hbA, pre0aBF, pre0a, 0u, 0u);
  mfma_nt<3><<<gemm_grid, 256, 0, stream>>>(
      v0m_bf, WpHi, WpLo, hbP, pre0pBF, pre0p, 0u, 0u);
  coef_ramp_kernel<<<dim3(BSZ), 256, 0, stream>>>(
      pre0a, pre0p, WTa, WTp, v0, vbA, vbP, tau, basis, unit,
      coefRe, coefIm, tmpA, tmpP, Ramp, Iph);

  // 2b) tau-column scatter: bf16 reads, coalesced gS writes, transpose-add
  csr_count<<<dim3(BSZ/256), 256, 0, stream>>>(tau, csrCnt);
  csr_scan <<<dim3(1), 1024, 0, stream>>>(csrCnt, csrOff, csrCur);
  csr_fill <<<dim3(BSZ/256), 256, 0, stream>>>(tau, csrCur, csrLst);
  scatter_v3<<<dim3(VN), 256, 0, stream>>>(
      pre0aBF, pre0pBF, WaTHi, WpTHi, tau, coefRe, coefIm,
      csrCnt, csrOff, csrLst, gSa, gSp);
  tadd_kernel<<<dim3(VN/32, HN/32), dim3(32,8), 0, stream>>>(
      gSa, gSp, gWa, gWp);

  // 3) CD-k Gibbs chain on matrix cores (bit-exact JAX partitionable
  //    threefry); fp32 v_cur written only at the LAST V-step
  for (int i = 0; i < NSTEPS; i++){
    unsigned kh0, kh1, kv0, kv1;
    tf2x32(0u, 1234u, 0u, (unsigned)(2*i),   kh0, kh1);
    tf2x32(0u, 1234u, 0u, (unsigned)(2*i+1), kv0, kv1);
    mfma_nt<0><<<gemm_grid, 256, 0, stream>>>(
        v_bf, WaHi, WaLo, hbA, h_bf, nullptr, kh0, kh1);
    if (i < NSTEPS-1)
      mfma_nt<0><<<gemm_grid, 256, 0, stream>>>(
          h_bf, WaTHi, WaTLo, vbA, v_bf, nullptr, kv0, kv1);
    else
      mfma_nt<1><<<gemm_grid, 256, 0, stream>>>(
          h_bf, WaTHi, WaTLo, vbA, v_bf, v_cur, kv0, kv1);
  }
  mfma_nt<2><<<gemm_grid, 256, 0, stream>>>(
      v_bf, WaHi, WaLo, hbA, nullptr, sig_k, 0u, 0u);

  // 4) transpose-convert gradient operands (with FUSED column sums),
  //    then split-K MFMA gradient GEMMs + fused finalize
  transpose_to_bf<<<tr_grid, tr_blk, 0, stream>>>(v0m,   v0mT,  csV0m);
  transpose_to_bf<<<tr_grid, tr_blk, 0, stream>>>(v_cur, vkT,   csVk);
  transpose_to_bf<<<tr_grid, tr_blk, 0, stream>>>(Ramp,  RampT, csRamp);
  transpose_to_bf<<<tr_grid, tr_blk, 0, stream>>>(Iph,   IphT,  csIph);
  transpose_to_bf<<<tr_grid, tr_blk, 0, stream>>>(sig_k, sigkT, csSigk);

  mfma_grad_split<2><<<dim3(VN/64, HN/64, 4), 256, 0, stream>>>(
      sigkT, vkT, RampT, v0mT, partA);
  mfma_grad_split<1><<<dim3(VN/64, HN/64, 4), 256, 0, stream>>>(
      IphT, v0mT, nullptr, nullptr, partP);
  finalize_grad<<<dim3(HN*VN/256), 256, 0, stream>>>(
      partA, partP, Wa, Wp, gWa, gWp);

  final_small<<<dim3(4), 256, 0, stream>>>(
      csV0m, csVk, csSigk, csRamp, csIph, tmpA, tmpP, gVa, gHa, gVp, gHp);
}

// Round 16
// 883.772 us; speedup vs baseline: 1.2923x; 1.0130x over previous
//
#include <hip/hip_runtime.h>
#include <cstdint>
#include <cstddef>

// Problem constants (fixed by the reference)
#define BSZ 4096
#define VN  1024
#define HN  1024
#define NSTEPS 10

static constexpr float INVB = 1.0f / 4096.0f;
static constexpr float L1R  = 1e-5f;
static constexpr float L2R  = 1e-4f;

typedef __attribute__((ext_vector_type(8)))  __bf16        bf16x8;
typedef __attribute__((ext_vector_type(8)))  unsigned short ushort8;
typedef __attribute__((ext_vector_type(4)))  unsigned short ushort4v;
typedef __attribute__((ext_vector_type(4)))  float          f32x4;
typedef __attribute__((ext_vector_type(16))) float          f32x16;

// ---------------------------------------------------------------------------
// bf16 helpers (RNE)
// ---------------------------------------------------------------------------
__device__ static inline unsigned short f2bf(float x){
  unsigned u = __float_as_uint(x);
  unsigned r = (u + 0x7FFFu + ((u >> 16) & 1u)) >> 16;
  return (unsigned short)r;
}
__device__ static inline float bf2f(unsigned short s){
  return __uint_as_float(((unsigned)s) << 16);
}

// async global->LDS, 16B per lane; LDS dest = wave-uniform base + lane*16
__device__ __forceinline__ void gload16(const void* g, void* l){
  __builtin_amdgcn_global_load_lds(
      (__attribute__((address_space(1))) void*)(g),
      (__attribute__((address_space(3))) void*)(l),
      16, 0, 0);
}

// ---------------------------------------------------------------------------
// Threefry-2x32 (bit-exact JAX PRNG)
// ---------------------------------------------------------------------------
#define TFR(x0,x1,r) { x0 += x1; x1 = ((x1)<<(r))|((x1)>>(32-(r))); x1 ^= x0; }

__host__ __device__ static inline void tf2x32(unsigned k0, unsigned k1,
                                              unsigned x0, unsigned x1,
                                              unsigned &o0, unsigned &o1)
{
  const unsigned ks2 = k0 ^ k1 ^ 0x1BD11BDAu;
  x0 += k0; x1 += k1;
  TFR(x0,x1,13) TFR(x0,x1,15) TFR(x0,x1,26) TFR(x0,x1,6)
  x0 += k1; x1 += ks2 + 1u;
  TFR(x0,x1,17) TFR(x0,x1,29) TFR(x0,x1,16) TFR(x0,x1,24)
  x0 += ks2; x1 += k0 + 2u;
  TFR(x0,x1,13) TFR(x0,x1,15) TFR(x0,x1,26) TFR(x0,x1,6)
  x0 += k0; x1 += k1 + 3u;
  TFR(x0,x1,17) TFR(x0,x1,29) TFR(x0,x1,16) TFR(x0,x1,24)
  x0 += k1; x1 += ks2 + 4u;
  TFR(x0,x1,13) TFR(x0,x1,15) TFR(x0,x1,26) TFR(x0,x1,6)
  x0 += ks2; x1 += k0 + 5u;
  o0 = x0; o1 = x1;
}

// jax.random.uniform element e — PARTITIONABLE threefry (JAX >= 0.4.30):
// counter (0, e); bits = xor-fold of the two outputs.
__device__ static inline float tf_uniform(unsigned k0, unsigned k1, unsigned e)
{
  unsigned o0, o1; tf2x32(k0, k1, 0u, e, o0, o1);
  const unsigned r = o0 ^ o1;
  return __uint_as_float((r >> 9) | 0x3f800000u) - 1.0f;
}

__device__ static inline float sigmoidf(float x){ return 1.0f/(1.0f+expf(-x)); }

// ---------------------------------------------------------------------------
// Small utility kernels
// ---------------------------------------------------------------------------
__global__ void zero_kernel(float* __restrict__ p, int n){
  int i = blockIdx.x*256 + threadIdx.x;
  if (i < n) p[i] = 0.0f;
}

// v0m = v0 with taus zeroed; v_cur=v0; bf16 copies for the MFMA path
__global__ void prep_kernel(const float* __restrict__ v0,
                            const int* __restrict__ tau,
                            float* __restrict__ v0m,
                            float* __restrict__ v_cur,
                            unsigned short* __restrict__ v0m_bf,
                            unsigned short* __restrict__ v_bf)
{
  int i = blockIdx.x*256 + threadIdx.x;     // exact grid BSZ*VN/256
  int b = i >> 10;
  int v = i & (VN-1);
  float x = v0[i];
  v_cur[i] = x;
  v_bf[i]  = f2bf(x);                        // 0/1 exact
  int t0 = tau[2*b], t1 = tau[2*b+1];
  float xm = (v==t0 || v==t1) ? 0.0f : x;
  v0m[i]    = xm;
  v0m_bf[i] = f2bf(xm);
}

// WT[v][h] = W[h][v] for both weight matrices (blockIdx.z selects)
__global__ void transpose_kernel(const float* __restrict__ Wa,
                                 const float* __restrict__ Wp,
                                 float* __restrict__ WTa,
                                 float* __restrict__ WTp)
{
  __shared__ float tile[32][33];
  const float* in = blockIdx.z ? Wp : Wa;
  float* out      = blockIdx.z ? WTp : WTa;
  int x  = blockIdx.x*32 + threadIdx.x;
  int y0 = blockIdx.y*32;
  for (int j = threadIdx.y; j < 32; j += 8)
    tile[j][threadIdx.x] = in[(size_t)(y0+j)*VN + x];
  __syncthreads();
  int xo  = y0 + threadIdx.x;
  int yo0 = blockIdx.x*32;
  for (int j = threadIdx.y; j < 32; j += 8)
    out[(size_t)(yo0+j)*HN + xo] = tile[threadIdx.x][j];
}

// 5-way batched: transpose fp32 [BSZ][1024] -> bf16 [1024][BSZ] + column sum.
// blockIdx.z selects which (X, XT, cs) triple. One dispatch replaces five.
__global__ void transpose_to_bf5(
    const float* __restrict__ X0, unsigned short* __restrict__ T0, float* __restrict__ c0,
    const float* __restrict__ X1, unsigned short* __restrict__ T1, float* __restrict__ c1,
    const float* __restrict__ X2, unsigned short* __restrict__ T2, float* __restrict__ c2,
    const float* __restrict__ X3, unsigned short* __restrict__ T3, float* __restrict__ c3,
    const float* __restrict__ X4, unsigned short* __restrict__ T4, float* __restrict__ c4)
{
  const float* X; unsigned short* XT; float* cs;
  switch (blockIdx.z){
    case 0: X=X0; XT=T0; cs=c0; break;
    case 1: X=X1; XT=T1; cs=c1; break;
    case 2: X=X2; XT=T2; cs=c2; break;
    case 3: X=X3; XT=T3; cs=c3; break;
    default:X=X4; XT=T4; cs=c4; break;
  }
  __shared__ float tile[32][33];
  const int tx = threadIdx.x, ty = threadIdx.y;
  int x  = blockIdx.x*32 + tx;            // col 0..1023
  int y0 = blockIdx.y*32;                 // row base 0..4095
  for (int j = ty; j < 32; j += 8)
    tile[j][tx] = X[(size_t)(y0+j)*1024 + x];
  __syncthreads();
  int xo  = y0 + tx;                      // b index in output row
  int yo0 = blockIdx.x*32;                // output row
  for (int j = ty; j < 32; j += 8)
    XT[(size_t)(yo0+j)*BSZ + xo] = f2bf(tile[tx][j]);
  float s = tile[ty][tx] + tile[ty+8][tx] + tile[ty+16][tx] + tile[ty+24][tx];
  __syncthreads();
  tile[ty][tx] = s;
  __syncthreads();
  if (ty == 0){
    float t = 0.f;
    #pragma unroll
    for (int j = 0; j < 8; j++) t += tile[j][tx];
    atomicAdd(cs + x, t);
  }
}

// hi/lo bf16 split of Wa, Wp, Wa^T; hi-only of Wp^T (for bf16 scatter)
__global__ void split_weights(const float* __restrict__ Wa,
                              const float* __restrict__ Wp,
                              const float* __restrict__ WTa,
                              const float* __restrict__ WTp,
                              unsigned short* __restrict__ WaHi,
                              unsigned short* __restrict__ WaLo,
                              unsigned short* __restrict__ WpHi,
                              unsigned short* __restrict__ WpLo,
                              unsigned short* __restrict__ WaTHi,
                              unsigned short* __restrict__ WaTLo,
                              unsigned short* __restrict__ WpTHi)
{
  size_t i = (size_t)blockIdx.x*256 + threadIdx.x;   // grid HN*VN/256
  float w = Wa[i];  unsigned short h = f2bf(w);
  WaHi[i] = h;  WaLo[i] = f2bf(w - bf2f(h));
  w = Wp[i];  h = f2bf(w);
  WpHi[i] = h;  WpLo[i] = f2bf(w - bf2f(h));
  w = WTa[i]; h = f2bf(w);
  WaTHi[i] = h; WaTLo[i] = f2bf(w - bf2f(h));
  WpTHi[i] = f2bf(WTp[i]);
}

// ---------------------------------------------------------------------------
// MFMA NT GEMM with hi/lo bf16 split B and fused epilogue (R12/R14 form).
// Tile 64x64, BK=64; 4 waves as 2x2 grid of 32x32 sub-tiles; 4 blocks/CU.
// K-accumulation order fixed -> bit-identical samples across rounds.
// MODE 0: sample -> bf16 out        (Gibbs H-step / V-steps 0..8)
// MODE 1: sample -> bf16 + fp32 out (last V-step)
// MODE 2: sigmoid -> fp32           (sig_k)
// ---------------------------------------------------------------------------
#define GM 64
#define GN 64
#define GK 64

template<int MODE>
__global__ __launch_bounds__(256) void mfma_nt(
    const unsigned short* __restrict__ A,     // [M][1024] bf16 (binary)
    const unsigned short* __restrict__ Bhi,   // [N][1024] bf16
    const unsigned short* __restrict__ Blo,   // [N][1024] bf16
    const float* __restrict__ bias,           // [N]
    unsigned short* __restrict__ out_bf,      // MODE 0,1
    float* __restrict__ out_f,                // MODE 1,2
    unsigned key0, unsigned key1)
{
  constexpr int K = 1024;
  constexpr int N = 1024;
  __shared__ ushort8 ldsA [GM*8];     // 8 KB
  __shared__ ushort8 ldsBh[GN*8];     // 8 KB
  __shared__ ushort8 ldsBl[GN*8];     // 8 KB

  // XCD-bijective swizzle: 1024 wgs / 8 XCDs = 128 contiguous per XCD
  const int orig = blockIdx.x + gridDim.x * blockIdx.y;
  const int swz  = (orig & 7) * 128 + (orig >> 3);
  const int bx   = swz & 15, by = swz >> 4;
  const int m0   = by*GM, n0 = bx*GN;

  const int tid  = threadIdx.x;
  const int lane = tid & 63, w = tid >> 6;
  const int wm = w >> 1, wn = w & 1;       // 2x2 wave grid over 32x32 tiles
  const int l31 = lane & 31, hi = lane >> 5;
  const int rsub = lane >> 3;         // 0..7
  const int cch  = lane & 7;          // chunk 0..7

  f32x16 acc = {};

  const int arow = wm*32 + l31;       // wave's 32-row A band   (0..63)
  const int brow = wn*32 + l31;       // wave's 32-row B band   (0..63)
  const int aswz = arow & 7;
  const int bswz = brow & 7;
  const int aidx = arow*8;
  const int bidx = brow*8;

  for (int kt = 0; kt < K/GK; ++kt){
    __syncthreads();
    const size_t kbase = (size_t)kt*GK;
    #pragma unroll
    for (int p = 0; p < 2; p++){
      const int row  = p*32 + w*8 + rsub;
      const int csrc = cch ^ (row & 7);
      gload16(A   + (size_t)(m0+row)*K + kbase + csrc*8, &ldsA [(p*32 + w*8)*8]);
      gload16(Bhi + (size_t)(n0+row)*K + kbase + csrc*8, &ldsBh[(p*32 + w*8)*8]);
      gload16(Blo + (size_t)(n0+row)*K + kbase + csrc*8, &ldsBl[(p*32 + w*8)*8]);
    }
    __syncthreads();   // drains vmcnt before barrier (compiler-inserted)

    #pragma unroll
    for (int s = 0; s < 4; s++){
      const int c = s*2 + hi;
      const bf16x8 a  = __builtin_bit_cast(bf16x8, ldsA [aidx + (c ^ aswz)]);
      const bf16x8 bh = __builtin_bit_cast(bf16x8, ldsBh[bidx + (c ^ bswz)]);
      const bf16x8 bl = __builtin_bit_cast(bf16x8, ldsBl[bidx + (c ^ bswz)]);
      acc = __builtin_amdgcn_mfma_f32_32x32x16_bf16(a, bh, acc, 0, 0, 0);
      acc = __builtin_amdgcn_mfma_f32_32x32x16_bf16(a, bl, acc, 0, 0, 0);
    }
  }

  // epilogue: C/D layout col=lane&31, row=(reg&3)+8*(reg>>2)+4*(lane>>5)
  const int n  = n0 + wn*32 + l31;
  const float bv = bias[n];
  const int mbase = m0 + wm*32 + 4*hi;
  #pragma unroll
  for (int r = 0; r < 16; r++){
    const int m = mbase + (r&3) + 8*(r>>2);
    const float pre = acc[r] + bv;
    const size_t o = (size_t)m*N + n;
    if constexpr (MODE == 0 || MODE == 1){
      const float p = sigmoidf(pre);
      const float u = tf_uniform(key0, key1, (unsigned)(m*N + n));
      out_bf[o] = (u < p) ? (unsigned short)0x3F80 : (unsigned short)0;
      if constexpr (MODE == 1) out_f[o] = (u < p) ? 1.0f : 0.0f;
    } else {
      out_f[o] = sigmoidf(pre);
    }
  }
}

// ---------------------------------------------------------------------------
// Dual-B variant for pre0: stages A (v0m_bf) ONCE, computes BOTH the amp and
// phase preactivations. LDS 40 KB -> still 4 blocks/CU. Per-acc K-order
// identical to the single kernel -> bit-identical pre0a/pre0p.
// ---------------------------------------------------------------------------
__global__ __launch_bounds__(256) void mfma_nt_dual(
    const unsigned short* __restrict__ A,
    const unsigned short* __restrict__ BhA, const unsigned short* __restrict__ BlA,
    const unsigned short* __restrict__ BhP, const unsigned short* __restrict__ BlP,
    const float* __restrict__ biasA, const float* __restrict__ biasP,
    float* __restrict__ outA, unsigned short* __restrict__ outAbf,
    float* __restrict__ outP, unsigned short* __restrict__ outPbf)
{
  constexpr int K = 1024;
  constexpr int N = 1024;
  __shared__ ushort8 ldsA  [GM*8];
  __shared__ ushort8 ldsBhA[GN*8];
  __shared__ ushort8 ldsBlA[GN*8];
  __shared__ ushort8 ldsBhP[GN*8];
  __shared__ ushort8 ldsBlP[GN*8];

  const int orig = blockIdx.x + gridDim.x * blockIdx.y;
  const int swz  = (orig & 7) * 128 + (orig >> 3);
  const int bx   = swz & 15, by = swz >> 4;
  const int m0   = by*GM, n0 = bx*GN;

  const int tid  = threadIdx.x;
  const int lane = tid & 63, w = tid >> 6;
  const int wm = w >> 1, wn = w & 1;
  const int l31 = lane & 31, hi = lane >> 5;
  const int rsub = lane >> 3;
  const int cch  = lane & 7;

  f32x16 accA = {}, accP = {};

  const int arow = wm*32 + l31;
  const int brow = wn*32 + l31;
  const int aswz = arow & 7;
  const int bswz = brow & 7;
  const int aidx = arow*8;
  const int bidx = brow*8;

  for (int kt = 0; kt < K/GK; ++kt){
    __syncthreads();
    const size_t kbase = (size_t)kt*GK;
    #pragma unroll
    for (int p = 0; p < 2; p++){
      const int row  = p*32 + w*8 + rsub;
      const int csrc = cch ^ (row & 7);
      gload16(A   + (size_t)(m0+row)*K + kbase + csrc*8, &ldsA  [(p*32 + w*8)*8]);
      gload16(BhA + (size_t)(n0+row)*K + kbase + csrc*8, &ldsBhA[(p*32 + w*8)*8]);
      gload16(BlA + (size_t)(n0+row)*K + kbase + csrc*8, &ldsBlA[(p*32 + w*8)*8]);
      gload16(BhP + (size_t)(n0+row)*K + kbase + csrc*8, &ldsBhP[(p*32 + w*8)*8]);
      gload16(BlP + (size_t)(n0+row)*K + kbase + csrc*8, &ldsBlP[(p*32 + w*8)*8]);
    }
    __syncthreads();

    #pragma unroll
    for (int s = 0; s < 4; s++){
      const int c = s*2 + hi;
      const bf16x8 a   = __builtin_bit_cast(bf16x8, ldsA  [aidx + (c ^ aswz)]);
      const bf16x8 bha = __builtin_bit_cast(bf16x8, ldsBhA[bidx + (c ^ bswz)]);
      const bf16x8 bla = __builtin_bit_cast(bf16x8, ldsBlA[bidx + (c ^ bswz)]);
      const bf16x8 bhp = __builtin_bit_cast(bf16x8, ldsBhP[bidx + (c ^ bswz)]);
      const bf16x8 blp = __builtin_bit_cast(bf16x8, ldsBlP[bidx + (c ^ bswz)]);
      accA = __builtin_amdgcn_mfma_f32_32x32x16_bf16(a, bha, accA, 0, 0, 0);
      accA = __builtin_amdgcn_mfma_f32_32x32x16_bf16(a, bla, accA, 0, 0, 0);
      accP = __builtin_amdgcn_mfma_f32_32x32x16_bf16(a, bhp, accP, 0, 0, 0);
      accP = __builtin_amdgcn_mfma_f32_32x32x16_bf16(a, blp, accP, 0, 0, 0);
    }
  }

  const int n  = n0 + wn*32 + l31;
  const float bvA = biasA[n], bvP = biasP[n];
  const int mbase = m0 + wm*32 + 4*hi;
  #pragma unroll
  for (int r = 0; r < 16; r++){
    const int m = mbase + (r&3) + 8*(r>>2);
    const size_t o = (size_t)m*N + n;
    const float pa = accA[r] + bvA;
    const float pp = accP[r] + bvP;
    outA[o] = pa;  outAbf[o] = f2bf(pa);
    outP[o] = pp;  outPbf[o] = f2bf(pp);
  }
}

// ---------------------------------------------------------------------------
// Split-K MFMA gradient GEMM (NT over transposed operands, K-slice 1024).
// grid (16,16,4) = 1024 blocks = 4/CU; gload16 staging (no bank conflicts).
// NPROD==2: part[z] = A1*B1^T - A2*B2^T   NPROD==1: part[z] = A1*B1^T
// ---------------------------------------------------------------------------
template<int NPROD>
__global__ __launch_bounds__(256) void mfma_grad_split(
    const unsigned short* __restrict__ A1,   // [1024][4096] bf16
    const unsigned short* __restrict__ B1,   // [1024][4096] bf16
    const unsigned short* __restrict__ A2,
    const unsigned short* __restrict__ B2,
    float* __restrict__ part)                // [4][HN][VN]
{
  constexpr int K = BSZ;
  __shared__ ushort8 lA1[64*8];
  __shared__ ushort8 lB1[64*8];
  __shared__ ushort8 lA2[(NPROD==2)?64*8:1];
  __shared__ ushort8 lB2[(NPROD==2)?64*8:1];

  const int tid  = threadIdx.x;
  const int m0   = blockIdx.y*64, n0 = blockIdx.x*64;
  const int kz   = blockIdx.z;                      // 0..3
  const int lane = tid & 63, w = tid >> 6;
  const int wm = w >> 1, wn = w & 1;
  const int l31 = lane & 31, hi = lane >> 5;
  const int rsub = lane >> 3;
  const int cch  = lane & 7;

  f32x16 acc1a = {}, acc1b = {}, acc2a = {}, acc2b = {};

  const int arow = wm*32 + l31;
  const int brow = wn*32 + l31;
  const int aswz = arow & 7, bswz = brow & 7;
  const int aidx = arow*8,  bidx = brow*8;

  for (int kt = 0; kt < 16; ++kt){
    __syncthreads();
    const size_t kbase = (size_t)kz*1024 + (size_t)kt*64;
    #pragma unroll
    for (int p = 0; p < 2; p++){
      const int row  = p*32 + w*8 + rsub;
      const int csrc = cch ^ (row & 7);
      gload16(A1 + (size_t)(m0+row)*K + kbase + csrc*8, &lA1[(p*32 + w*8)*8]);
      gload16(B1 + (size_t)(n0+row)*K + kbase + csrc*8, &lB1[(p*32 + w*8)*8]);
      if constexpr (NPROD==2){
        gload16(A2 + (size_t)(m0+row)*K + kbase + csrc*8, &lA2[(p*32 + w*8)*8]);
        gload16(B2 + (size_t)(n0+row)*K + kbase + csrc*8, &lB2[(p*32 + w*8)*8]);
      }
    }
    __syncthreads();
    #pragma unroll
    for (int s = 0; s < 4; s++){
      const int c = s*2 + hi;
      const bf16x8 a1 = __builtin_bit_cast(bf16x8, lA1[aidx + (c ^ aswz)]);
      const bf16x8 b1 = __builtin_bit_cast(bf16x8, lB1[bidx + (c ^ bswz)]);
      if (s & 1) acc1b = __builtin_amdgcn_mfma_f32_32x32x16_bf16(a1, b1, acc1b, 0,0,0);
      else       acc1a = __builtin_amdgcn_mfma_f32_32x32x16_bf16(a1, b1, acc1a, 0,0,0);
      if constexpr (NPROD==2){
        const bf16x8 a2 = __builtin_bit_cast(bf16x8, lA2[aidx + (c ^ aswz)]);
        const bf16x8 b2 = __builtin_bit_cast(bf16x8, lB2[bidx + (c ^ bswz)]);
        if (s & 1) acc2b = __builtin_amdgcn_mfma_f32_32x32x16_bf16(a2, b2, acc2b, 0,0,0);
        else       acc2a = __builtin_amdgcn_mfma_f32_32x32x16_bf16(a2, b2, acc2a, 0,0,0);
      }
    }
  }

  float* outp = part + (size_t)kz * HN * VN;
  const int n = n0 + wn*32 + l31;
  #pragma unroll
  for (int r = 0; r < 16; r++){
    const int m = m0 + wm*32 + 4*hi + (r&3) + 8*(r>>2);
    const size_t o = (size_t)m*VN + n;
    if constexpr (NPROD==2)
      outp[o] = (acc1a[r]+acc1b[r]) - (acc2a[r]+acc2b[r]);
    else
      outp[o] = acc1a[r]+acc1b[r];
  }
}

// finalize: gW += INVB*sum_z(part) + L2*W + L1*sign(W)   (both matrices)
__global__ __launch_bounds__(256) void finalize_grad(
    const float* __restrict__ partA, const float* __restrict__ partP,
    const float* __restrict__ Wa,    const float* __restrict__ Wp,
    float* __restrict__ gWa, float* __restrict__ gWp)
{
  const size_t i  = (size_t)blockIdx.x*256 + threadIdx.x;
  const size_t MN = (size_t)HN*VN;
  const float sA = ((partA[i] + partA[MN+i]) + partA[2*MN+i]) + partA[3*MN+i];
  const float sP = ((partP[i] + partP[MN+i]) + partP[2*MN+i]) + partP[3*MN+i];
  const float wa = Wa[i], wp = Wp[i];
  const float sga = (wa>0.f)?1.f:((wa<0.f)?-1.f:0.f);
  const float sgp = (wp>0.f)?1.f:((wp<0.f)?-1.f:0.f);
  gWa[i] += INVB*sA + L2R*wa + L1R*sga;
  gWp[i] += INVB*sP + L2R*wp + L1R*sgp;
}

// ---------------------------------------------------------------------------
// Fused coef + ramp kernel (Taylor-3 differentials + fp64 tail; see R7)
// ---------------------------------------------------------------------------
__global__ __launch_bounds__(256) void coef_ramp_kernel(
    const float* __restrict__ pre0a, const float* __restrict__ pre0p,
    const float* __restrict__ WTa,   const float* __restrict__ WTp,
    const float* __restrict__ v0,
    const float* __restrict__ vbA,   const float* __restrict__ vbP,
    const int*   __restrict__ tau,   const int*   __restrict__ basis,
    const float* __restrict__ unit,
    float* __restrict__ coefRe, float* __restrict__ coefIm,
    float* __restrict__ tmpA,   float* __restrict__ tmpP,
    float* __restrict__ Ramp,   float* __restrict__ Iph)
{
  const int b = blockIdx.x;
  const int t = threadIdx.x;
  const int t0 = tau[2*b], t1 = tau[2*b+1];

  float d[6] = {0,0,0,0,0,0};
  float st_sa[4], st_sp[4], st_a0[4], st_a1[4], st_p0[4], st_p1[4];

  #pragma unroll
  for (int i = 0; i < 4; i++){
    const int h = t + i*256;
    const float pa = pre0a[(size_t)b*HN + h], pp = pre0p[(size_t)b*HN + h];
    const float a0 = WTa[(size_t)t0*HN + h], a1 = WTa[(size_t)t1*HN + h];
    const float p0 = WTp[(size_t)t0*HN + h], p1 = WTp[(size_t)t1*HN + h];
    const float sa  = sigmoidf(pa);
    const float sp  = sigmoidf(pp);
    const float s1a = sa*(1.f-sa), ta2 = 1.f-2.f*sa, s2a = s1a*ta2;
    const float s1p = sp*(1.f-sp), tp2 = 1.f-2.f*sp, s2p = s1p*tp2;
    const float a01 = a0 + a1, p01 = p0 + p1;
    d[0] += a1 *(sa + a1 *(0.5f*s1a + 0.16666667f*a1 *s2a));
    d[1] += a0 *(sa + a0 *(0.5f*s1a + 0.16666667f*a0 *s2a));
    d[2] += a01*(sa + a01*(0.5f*s1a + 0.16666667f*a01*s2a));
    d[3] += p1 *(sp + p1 *(0.5f*s1p + 0.16666667f*p1 *s2p));
    d[4] += p0 *(sp + p0 *(0.5f*s1p + 0.16666667f*p0 *s2p));
    d[5] += p01*(sp + p01*(0.5f*s1p + 0.16666667f*p01*s2p));
    st_sa[i]=sa; st_sp[i]=sp; st_a0[i]=a0; st_a1[i]=a1; st_p0[i]=p0; st_p1[i]=p1;
  }

  __shared__ float red[6][4];
  __shared__ float lcr[4], lci[4];
  const int lane = t & 63, wv = t >> 6;
  #pragma unroll
  for (int i=0;i<6;i++){
    float x = d[i];
    for (int off=32; off>0; off>>=1) x += __shfl_down(x, off);
    if (lane==0) red[i][wv] = x;
  }
  __syncthreads();

  if (t==0){
    double ds[6];
    #pragma unroll
    for (int i=0;i<6;i++)
      ds[i] = (double)red[i][0]+red[i][1]+red[i][2]+red[i][3];

    const int bas0 = basis[(size_t)b*VN + t0], bas1 = basis[(size_t)b*VN + t1];
    const int x0 = (int)v0[(size_t)b*VN + t0], x1 = (int)v0[(size_t)b*VN + t1];
    const double A0 = vbA[t0], A1 = vbA[t1], P0 = vbP[t0], P1 = vbP[t1];

    double la[4], th[4];
    la[0]=0.0;                th[0]=0.0;
    la[1]=0.5*(A1+ds[0]);     th[1]=0.5*(P1+ds[3]);
    la[2]=0.5*(A0+ds[1]);     th[2]=0.5*(P0+ds[4]);
    la[3]=0.5*(A0+A1+ds[2]);  th[3]=0.5*(P0+P1+ds[5]);

    double wR[4], wI[4], sr=0.0, si=0.0;
    #pragma unroll
    for (int c=0;c<4;c++){
      const int s0 = (c>>1)&1, s1 = c&1;
      const float* u0 = unit + (((size_t)bas0*2 + x0)*2 + s0)*2;
      const float* u1 = unit + (((size_t)bas1*2 + x1)*2 + s1)*2;
      const double uR = (double)u0[0]*u1[0] - (double)u0[1]*u1[1];
      const double uI = (double)u0[0]*u1[1] + (double)u0[1]*u1[0];
      const double e  = exp(la[c]);
      const double cs = cos(th[c]), sn = sin(th[c]);
      wR[c] = e*(uR*cs - uI*sn);
      wI[c] = e*(uR*sn + uI*cs);
      sr += wR[c]; si += wI[c];
    }
    const double dd = sr*sr + si*si;
    #pragma unroll
    for (int c=0;c<4;c++){
      const float cr = (float)((wR[c]*sr + wI[c]*si)/dd);
      const float ci = (float)((wI[c]*sr - wR[c]*si)/dd);
      coefRe[b*4+c] = cr;  coefIm[b*4+c] = ci;
      lcr[c] = cr;         lci[c] = ci;
    }
    atomicAdd(tmpA + t0, lcr[2]+lcr[3]);
    atomicAdd(tmpA + t1, lcr[1]+lcr[3]);
    atomicAdd(tmpP + t0, lci[2]+lci[3]);
    atomicAdd(tmpP + t1, lci[1]+lci[3]);
  }
  __syncthreads();

  const float cr0=lcr[0], cr1=lcr[1], cr2=lcr[2], cr3=lcr[3];
  const float ci0=lci[0], ci1=lci[1], ci2=lci[2], ci3=lci[3];

  #pragma unroll
  for (int i = 0; i < 4; i++){
    const int h = t + i*256;
    const float sa = st_sa[i], sp = st_sp[i];
    const float a0 = st_a0[i], a1 = st_a1[i], p0 = st_p0[i], p1 = st_p1[i];
    const float s1a = sa*(1.f-sa), ta2 = 1.f-2.f*sa;
    const float s2a = s1a*ta2,     s3a = s1a*(ta2*ta2 - 2.f*s1a);
    const float s1p = sp*(1.f-sp), tp2 = 1.f-2.f*sp;
    const float s2p = s1p*tp2,     s3p = s1p*(tp2*tp2 - 2.f*s1p);
    const float a01 = a0 + a1, p01 = p0 + p1;
    const float sgA1 = sa + a1 *(s1a + a1 *(0.5f*s2a + 0.16666667f*a1 *s3a));
    const float sgA0 = sa + a0 *(s1a + a0 *(0.5f*s2a + 0.16666667f*a0 *s3a));
    const float sgA01= sa + a01*(s1a + a01*(0.5f*s2a + 0.16666667f*a01*s3a));
    const float sgP1 = sp + p1 *(s1p + p1 *(0.5f*s2p + 0.16666667f*p1 *s3p));
    const float sgP0 = sp + p0 *(s1p + p0 *(0.5f*s2p + 0.16666667f*p0 *s3p));
    const float sgP01= sp + p01*(s1p + p01*(0.5f*s2p + 0.16666667f*p01*s3p));
    Ramp[(size_t)b*HN + h] = cr0*sa + cr1*sgA1 + cr2*sgA0 + cr3*sgA01;
    Iph [(size_t)b*HN + h] = ci0*sp + ci1*sgP1 + ci2*sgP0 + ci3*sgP01;
  }
}

// ---------------------------------------------------------------------------
// CSR build + grouped tau-column scatter (bf16 operands, coalesced output)
// ---------------------------------------------------------------------------
__global__ void csr_count(const int* __restrict__ tau, int* __restrict__ cnt){
  int b = blockIdx.x*256 + threadIdx.x;
  atomicAdd(cnt + tau[2*b],   1);
  atomicAdd(cnt + tau[2*b+1], 1);
}

__global__ __launch_bounds__(1024) void csr_scan(const int* __restrict__ cnt,
                                                 int* __restrict__ off,
                                                 int* __restrict__ cur){
  __shared__ int s[1024];
  const int t = threadIdx.x;
  s[t] = cnt[t];
  __syncthreads();
  for (int d=1; d<1024; d<<=1){
    int v = 0;
    if (t >= d) v = s[t-d];
    __syncthreads();
    s[t] += v;
    __syncthreads();
  }
  const int excl = (t==0) ? 0 : s[t-1];
  off[t] = excl; cur[t] = excl;
}

__global__ void csr_fill(const int* __restrict__ tau, int* __restrict__ cur,
                         int* __restrict__ list){
  int b = blockIdx.x*256 + threadIdx.x;
  int p0 = atomicAdd(cur + tau[2*b],   1); list[p0] = b;
  int p1 = atomicAdd(cur + tau[2*b+1], 1); list[p1] = b;
}

// grid (VN, 4): block (v, h-quarter), 1 h per thread -> 4x TLP vs R15's
// one-block-per-v (latency-bound serial e-loop, VALUBusy 47% @ Occ 19%).
// Per-output accumulation order over e unchanged -> bit-identical.
__global__ __launch_bounds__(256) void scatter_v4(
    const unsigned short* __restrict__ pre0aBF,
    const unsigned short* __restrict__ pre0pBF,
    const unsigned short* __restrict__ WaTHi,
    const unsigned short* __restrict__ WpTHi,
    const int*   __restrict__ tau,
    const float* __restrict__ coefRe, const float* __restrict__ coefIm,
    const int* __restrict__ cnt, const int* __restrict__ off,
    const int* __restrict__ list,
    float* __restrict__ gSa, float* __restrict__ gSp)
{
  const int v = blockIdx.x;
  const int h = blockIdx.y*256 + threadIdx.x;
  const int n = cnt[v];
  const int o = off[v];
  const int c_lo = (v < 512) ? 2 : 1;
  const bool lo_half = (v < 512);

  float accA = 0.f, accP = 0.f;
  if (n > 0){
    const float av = bf2f(WaTHi[(size_t)v*HN + h]);
    const float pv = bf2f(WpTHi[(size_t)v*HN + h]);
    for (int e = o; e < o + n; e++){
      const int b  = list[e];
      const int ot = lo_half ? tau[2*b+1] : tau[2*b];
      const float ao  = bf2f(WaTHi[(size_t)ot*HN + h]);
      const float po  = bf2f(WpTHi[(size_t)ot*HN + h]);
      const float paf = bf2f(pre0aBF[(size_t)b*HN + h]) + av;
      const float ppf = bf2f(pre0pBF[(size_t)b*HN + h]) + pv;
      const float crl = coefRe[b*4 + c_lo], cr3 = coefRe[b*4 + 3];
      const float cil = coefIm[b*4 + c_lo], ci3 = coefIm[b*4 + 3];
      accA += crl*sigmoidf(paf) + cr3*sigmoidf(paf + ao);
      accP += cil*sigmoidf(ppf) + ci3*sigmoidf(ppf + po);
    }
  }
  gSa[(size_t)v*HN + h] = accA;
  gSp[(size_t)v*HN + h] = accP;
}

// transpose-add: gWa[h][v] = -INVB*gSa[v][h]; gWp[h][v] = INVB*gSp[v][h].
__global__ void tadd_kernel(const float* __restrict__ gSa,
                            const float* __restrict__ gSp,
                            float* __restrict__ gWa,
                            float* __restrict__ gWp)
{
  __shared__ float ta[32][33], tp[32][33];
  const int tx = threadIdx.x, ty = threadIdx.y;   // (32,8)
  const int v0 = blockIdx.x*32, h0 = blockIdx.y*32;
  for (int j = ty; j < 32; j += 8){
    ta[j][tx] = gSa[(size_t)(v0+j)*HN + h0 + tx];
    tp[j][tx] = gSp[(size_t)(v0+j)*HN + h0 + tx];
  }
  __syncthreads();
  for (int j = ty; j < 32; j += 8){
    gWa[(size_t)(h0+j)*VN + v0 + tx] = -INVB*ta[tx][j];
    gWp[(size_t)(h0+j)*VN + v0 + tx] =  INVB*tp[tx][j];
  }
}

__global__ void final_small(
    const float* __restrict__ csV0m, const float* __restrict__ csVk,
    const float* __restrict__ csSigk, const float* __restrict__ csRamp,
    const float* __restrict__ csIph,
    const float* __restrict__ tmpA, const float* __restrict__ tmpP,
    float* __restrict__ gVa, float* __restrict__ gHa,
    float* __restrict__ gVp, float* __restrict__ gHp)
{
  const int j = blockIdx.x*256 + threadIdx.x;
  if (j < VN){
    gVa[j] = INVB*(csVk[j] - csV0m[j] - tmpA[j]);
    gVp[j] = INVB*tmpP[j];
  }
  if (j < HN){
    gHa[j] = INVB*(csSigk[j] - csRamp[j]);
    gHp[j] = INVB*csIph[j];
  }
}

// ---------------------------------------------------------------------------
extern "C" void kernel_launch(void* const* d_in, const int* in_sizes, int n_in,
                              void* d_out, int out_size, void* d_ws, size_t ws_size,
                              hipStream_t stream)
{
  const float* v0    = (const float*)d_in[0];
  const int*   basis = (const int*)  d_in[1];
  const int*   tau   = (const int*)  d_in[2];
  const float* unit  = (const float*)d_in[3];
  const float* Wa    = (const float*)d_in[4];
  const float* vbA   = (const float*)d_in[5];
  const float* hbA   = (const float*)d_in[6];
  const float* Wp    = (const float*)d_in[7];
  const float* vbP   = (const float*)d_in[8];
  const float* hbP   = (const float*)d_in[9];

  // workspace layout (~158 MB)
  float* ws    = (float*)d_ws;
  float* v0m   = ws;  ws += (size_t)BSZ*VN;   // -> partA after transpose_to_bf5
  float* v_cur = ws;  ws += (size_t)BSZ*VN;   // -> partP after transpose_to_bf5
  float* h_buf = ws;  ws += (size_t)BSZ*HN;   // pre0 bf16 copies, later sig_k
  float* WTa   = ws;  ws += (size_t)VN*HN;    // } dead after coef_ramp/scatter
  float* WTp   = ws;  ws += (size_t)VN*HN;    // }   -> sigkT (8MB)
  float* pre0a = ws;  ws += (size_t)BSZ*HN;   // -> gSa/gSp, then v0mT/vkT
  float* pre0p = ws;  ws += (size_t)BSZ*HN;   // -> RampT/IphT
  float* Ramp  = ws;  ws += (size_t)BSZ*HN;
  float* Iph   = ws;  ws += (size_t)BSZ*HN;
  float* coefRe= ws;  ws += (size_t)BSZ*4;
  float* coefIm= ws;  ws += (size_t)BSZ*4;
  float* tmpA  = ws;  ws += VN;
  float* tmpP  = ws;  ws += VN;
  float* csV0m = ws;  ws += VN;
  float* csVk  = ws;  ws += VN;
  float* csSigk= ws;  ws += HN;
  float* csRamp= ws;  ws += HN;
  float* csIph = ws;  ws += HN;
  int*   csrCnt = (int*)ws;  ws += VN;
  int*   csrOff = (int*)ws;  ws += VN;
  int*   csrCur = (int*)ws;  ws += VN;
  int*   csrLst = (int*)ws;  ws += 2*BSZ;
  // bf16 buffers
  unsigned short* v_bf    = (unsigned short*)ws;  ws += (size_t)BSZ*VN/2;
  unsigned short* h_bf    = (unsigned short*)ws;  ws += (size_t)BSZ*HN/2;
  unsigned short* v0m_bf  = (unsigned short*)ws;  ws += (size_t)BSZ*VN/2;
  unsigned short* WaHi    = (unsigned short*)ws;  ws += (size_t)HN*VN/2;
  unsigned short* WaLo    = (unsigned short*)ws;  ws += (size_t)HN*VN/2;
  unsigned short* WpHi    = (unsigned short*)ws;  ws += (size_t)HN*VN/2;
  unsigned short* WpLo    = (unsigned short*)ws;  ws += (size_t)HN*VN/2;
  unsigned short* WaTHi   = (unsigned short*)ws;  ws += (size_t)HN*VN/2;
  unsigned short* WaTLo   = (unsigned short*)ws;  ws += (size_t)HN*VN/2;
  unsigned short* WpTHi   = (unsigned short*)ws;  ws += (size_t)HN*VN/2;

  float* sig_k = h_buf;
  unsigned short* pre0aBF = (unsigned short*)h_buf;
  unsigned short* pre0pBF = pre0aBF + (size_t)BSZ*HN;
  float* gSa = pre0a;
  float* gSp = pre0a + (size_t)VN*HN;
  unsigned short* v0mT  = (unsigned short*)pre0a;                  // 8 MB
  unsigned short* vkT   = v0mT + (size_t)VN*BSZ;                   // 8 MB
  unsigned short* RampT = (unsigned short*)pre0p;                  // 8 MB
  unsigned short* IphT  = RampT + (size_t)HN*BSZ;                  // 8 MB
  unsigned short* sigkT = (unsigned short*)WTa;                    // 8 MB
  float* partA = v0m;                          // [4][HN][VN] = 16 MB
  float* partP = v_cur;                        // [4][HN][VN] = 16 MB

  float* out = (float*)d_out;
  float* gWa = out;
  float* gVa = gWa + (size_t)HN*VN;
  float* gHa = gVa + VN;
  float* gWp = gHa + HN;
  float* gVp = gWp + (size_t)HN*VN;
  float* gHp = gVp + VN;

  const dim3 gemm_grid(VN/GN, BSZ/GM);   // (16, 64) = 1024 wgs, 4/CU
  const dim3 tr_grid(1024/32, BSZ/32, 5);
  const dim3 tr_blk(32, 8);

  // 1) init
  zero_kernel<<<dim3(40), 256, 0, stream>>>(tmpA, 10*1024);
  prep_kernel<<<dim3(BSZ*VN/256), 256, 0, stream>>>(v0, tau, v0m, v_cur, v0m_bf, v_bf);
  transpose_kernel<<<dim3(VN/32, HN/32, 2), dim3(32,8), 0, stream>>>(Wa, Wp, WTa, WTp);
  split_weights<<<dim3(HN*VN/256), 256, 0, stream>>>(
      Wa, Wp, WTa, WTp, WaHi, WaLo, WpHi, WpLo, WaTHi, WaTLo, WpTHi);

  // 2) positive phase: BOTH pre0 GEMMs fused (A staged once), coef+ramp
  mfma_nt_dual<<<gemm_grid, 256, 0, stream>>>(
      v0m_bf, WaHi, WaLo, WpHi, WpLo, hbA, hbP,
      pre0a, pre0aBF, pre0p, pre0pBF);
  coef_ramp_kernel<<<dim3(BSZ), 256, 0, stream>>>(
      pre0a, pre0p, WTa, WTp, v0, vbA, vbP, tau, basis, unit,
      coefRe, coefIm, tmpA, tmpP, Ramp, Iph);

  // 2b) tau-column scatter: bf16 reads, coalesced gS writes, transpose-add
  csr_count<<<dim3(BSZ/256), 256, 0, stream>>>(tau, csrCnt);
  csr_scan <<<dim3(1), 1024, 0, stream>>>(csrCnt, csrOff, csrCur);
  csr_fill <<<dim3(BSZ/256), 256, 0, stream>>>(tau, csrCur, csrLst);
  scatter_v4<<<dim3(VN, 4), 256, 0, stream>>>(
      pre0aBF, pre0pBF, WaTHi, WpTHi, tau, coefRe, coefIm,
      csrCnt, csrOff, csrLst, gSa, gSp);
  tadd_kernel<<<dim3(VN/32, HN/32), dim3(32,8), 0, stream>>>(
      gSa, gSp, gWa, gWp);

  // 3) CD-k Gibbs chain on matrix cores (bit-exact JAX partitionable
  //    threefry); fp32 v_cur written only at the LAST V-step
  for (int i = 0; i < NSTEPS; i++){
    unsigned kh0, kh1, kv0, kv1;
    tf2x32(0u, 1234u, 0u, (unsigned)(2*i),   kh0, kh1);
    tf2x32(0u, 1234u, 0u, (unsigned)(2*i+1), kv0, kv1);
    mfma_nt<0><<<gemm_grid, 256, 0, stream>>>(
        v_bf, WaHi, WaLo, hbA, h_bf, nullptr, kh0, kh1);
    if (i < NSTEPS-1)
      mfma_nt<0><<<gemm_grid, 256, 0, stream>>>(
          h_bf, WaTHi, WaTLo, vbA, v_bf, nullptr, kv0, kv1);
    else
      mfma_nt<1><<<gemm_grid, 256, 0, stream>>>(
          h_bf, WaTHi, WaTLo, vbA, v_bf, v_cur, kv0, kv1);
  }
  mfma_nt<2><<<gemm_grid, 256, 0, stream>>>(
      v_bf, WaHi, WaLo, hbA, nullptr, sig_k, 0u, 0u);

  // 4) batched transpose-convert (fused column sums), split-K grads, finalize
  transpose_to_bf5<<<tr_grid, tr_blk, 0, stream>>>(
      v0m,   v0mT,  csV0m,
      v_cur, vkT,   csVk,
      Ramp,  RampT, csRamp,
      Iph,   IphT,  csIph,
      sig_k, sigkT, csSigk);

  mfma_grad_split<2><<<dim3(VN/64, HN/64, 4), 256, 0, stream>>>(
      sigkT, vkT, RampT, v0mT, partA);
  mfma_grad_split<1><<<dim3(VN/64, HN/64, 4), 256, 0, stream>>>(
      IphT, v0mT, nullptr, nullptr, partP);
  finalize_grad<<<dim3(HN*VN/256), 256, 0, stream>>>(
      partA, partP, Wa, Wp, gWa, gWp);

  final_small<<<dim3(4), 256, 0, stream>>>(
      csV0m, csVk, csSigk, csRamp, csIph, tmpA, tmpP, gVa, gHa, gVp, gHp);
}